// Round 1
// baseline (904.748 us; speedup 1.0000x reference)
//
#include <hip/hip_runtime.h>

#define CKD 512
#define NROWS 44

static __device__ __forceinline__ int imin(int a, int b) { return a < b ? a : b; }

// ---------------------------------------------------------------------------
// GEMM: Out[m][n] = sum_k A[row(m)][k] * W[n][k] + bias[n]   (K = N = 512)
// mode 0: Lk0, M = 4*4096, source row wraps (t >= 3072 -> t-3072), out pitch 4096/b
// mode 1: Lk1, M = 4*3072, source rows from pitch-4096 buffer
// ---------------------------------------------------------------------------
__global__ __launch_bounds__(256) void k_gemm512(
    const float* __restrict__ A, const float* __restrict__ W,
    const float* __restrict__ bias, float* __restrict__ Out, int mode)
{
  __shared__ float As[16][68];
  __shared__ float Ws[16][68];
  const int tid = threadIdx.x;
  const int lr = tid >> 2;           // 0..63 row within tile
  const int lk = (tid & 3) << 2;     // 0,4,8,12
  const int tm = tid >> 4, tn = tid & 15;

  int gm = (blockIdx.x << 6) + lr;
  int arow;
  if (mode == 0) {
    int b = gm >> 12;
    int t = gm & 4095;
    if (t >= 3072) t -= 3072;
    arow = b * 3072 + t;
  } else {
    int b = gm / 3072;
    int t = gm - b * 3072;
    arow = (b << 12) + t;
  }
  const float* Ap = A + (size_t)arow * CKD;
  const float* Wp = W + (size_t)((blockIdx.y << 6) + lr) * CKD;

  float acc[4][4] = {};
  for (int k0 = 0; k0 < CKD; k0 += 16) {
    float4 av = *(const float4*)(Ap + k0 + lk);
    float4 wv = *(const float4*)(Wp + k0 + lk);
    __syncthreads();
    As[lk + 0][lr] = av.x; As[lk + 1][lr] = av.y; As[lk + 2][lr] = av.z; As[lk + 3][lr] = av.w;
    Ws[lk + 0][lr] = wv.x; Ws[lk + 1][lr] = wv.y; Ws[lk + 2][lr] = wv.z; Ws[lk + 3][lr] = wv.w;
    __syncthreads();
#pragma unroll
    for (int kk = 0; kk < 16; ++kk) {
      float4 a4 = *(const float4*)&As[kk][tm << 2];
      float4 w4 = *(const float4*)&Ws[kk][tn << 2];
      float aa[4] = {a4.x, a4.y, a4.z, a4.w};
      float ww[4] = {w4.x, w4.y, w4.z, w4.w};
#pragma unroll
      for (int ii = 0; ii < 4; ++ii)
#pragma unroll
        for (int jj = 0; jj < 4; ++jj) acc[ii][jj] += aa[ii] * ww[jj];
    }
  }
  const int om = (blockIdx.x << 6) + (tm << 2);
  const int on = (blockIdx.y << 6) + (tn << 2);
  float4 b4 = *(const float4*)(bias + on);
#pragma unroll
  for (int ii = 0; ii < 4; ++ii) {
    float4 r;
    r.x = acc[ii][0] + b4.x; r.y = acc[ii][1] + b4.y;
    r.z = acc[ii][2] + b4.z; r.w = acc[ii][3] + b4.w;
    *(float4*)(Out + (size_t)(om + ii) * CKD + on) = r;
  }
}

// ---------------------------------------------------------------------------
// Decomposition step: xa = [v[2s], v[2s+1]] (16), d = xa@ec_d, v' = xa@ec_s
// one thread per (b, s, c)
// ---------------------------------------------------------------------------
__global__ __launch_bounds__(256) void k_decomp(
    const float* __restrict__ Vin, const float* __restrict__ ec_s,
    const float* __restrict__ ec_d, float* __restrict__ Dout,
    float* __restrict__ Vout, int Lout, int pin)
{
  __shared__ float Es[128], Ed[128];
  if (threadIdx.x < 128) Es[threadIdx.x] = ec_s[threadIdx.x];
  else Ed[threadIdx.x - 128] = ec_d[threadIdx.x - 128];
  __syncthreads();
  int g = blockIdx.x * 256 + threadIdx.x;
  if (g >= 4 * Lout * 64) return;
  int c = g & 63;
  int s = (g >> 6) % Lout;
  int b = g / (Lout << 6);
  const float* r0 = Vin + ((size_t)b * pin + 2 * s) * CKD + (c << 3);
  float a[16];
  float4 v0 = *(const float4*)r0;
  float4 v1 = *(const float4*)(r0 + 4);
  float4 v2 = *(const float4*)(r0 + CKD);
  float4 v3 = *(const float4*)(r0 + CKD + 4);
  a[0]=v0.x; a[1]=v0.y; a[2]=v0.z; a[3]=v0.w; a[4]=v1.x; a[5]=v1.y; a[6]=v1.z; a[7]=v1.w;
  a[8]=v2.x; a[9]=v2.y; a[10]=v2.z; a[11]=v2.w; a[12]=v3.x; a[13]=v3.y; a[14]=v3.z; a[15]=v3.w;
  float dv[8] = {}, vv[8] = {};
#pragma unroll
  for (int m = 0; m < 16; ++m)
#pragma unroll
    for (int k = 0; k < 8; ++k) {
      dv[k] += a[m] * Ed[m * 8 + k];
      vv[k] += a[m] * Es[m * 8 + k];
    }
  size_t orow = ((size_t)b * Lout + s) * CKD + (c << 3);
  *(float4*)(Dout + orow)     = make_float4(dv[0], dv[1], dv[2], dv[3]);
  *(float4*)(Dout + orow + 4) = make_float4(dv[4], dv[5], dv[6], dv[7]);
  *(float4*)(Vout + orow)     = make_float4(vv[0], vv[1], vv[2], vv[3]);
  *(float4*)(Vout + orow + 4) = make_float4(vv[4], vv[5], vv[6], vv[7]);
}

// ---------------------------------------------------------------------------
// T0: out[...,ko] = sum_k v[...,k]*T0_w[ko,k] + T0_b[ko]  on v_11 (B,2,64,8)
// ---------------------------------------------------------------------------
__global__ __launch_bounds__(256) void k_t0(
    const float* __restrict__ Vin, const float* __restrict__ T0w,
    const float* __restrict__ T0b, float* __restrict__ Out)
{
  int g = blockIdx.x * 256 + threadIdx.x;
  if (g >= 4 * 2 * 64) return;
  int c = g & 63;
  int t = (g >> 6) & 1;
  int b = g >> 7;
  const float* src = Vin + ((size_t)(b * 2 + t)) * CKD + (c << 3);
  float a[8];
  float4 v0 = *(const float4*)src;
  float4 v1 = *(const float4*)(src + 4);
  a[0]=v0.x; a[1]=v0.y; a[2]=v0.z; a[3]=v0.w; a[4]=v1.x; a[5]=v1.y; a[6]=v1.z; a[7]=v1.w;
  float o[8];
#pragma unroll
  for (int ko = 0; ko < 8; ++ko) {
    float sum = T0b[ko];
#pragma unroll
    for (int k = 0; k < 8; ++k) sum += a[k] * T0w[ko * 8 + k];
    o[ko] = sum;
  }
  float* dst = Out + ((size_t)(b * 2 + t)) * CKD + (c << 3);
  *(float4*)dst       = make_float4(o[0], o[1], o[2], o[3]);
  *(float4*)(dst + 4) = make_float4(o[4], o[5], o[6], o[7]);
}

// ---------------------------------------------------------------------------
// Forward truncated DFT: X[f][r][i] = sum_t src[b,t,i] * e^{-2pi i f t / L}
// grid.x enumerates (level j, 128-t chunk); grid.y = b; grid.z: 0=d arena, 1=v arena
// chunk partials accumulated with atomicAdd (X pre-zeroed)
// ---------------------------------------------------------------------------
__global__ __launch_bounds__(256) void k_fdft(
    const float* __restrict__ DD, const float* __restrict__ VD,
    float* __restrict__ XDre, float* __restrict__ XDim,
    float* __restrict__ XVre, float* __restrict__ XVim)
{
  __shared__ float2 tw[2048];  // [f][128]
  int bx = blockIdx.x, j = 1;
  for (;;) {
    int c = (4096 >> j) >> 7; if (c < 1) c = 1;
    if (bx < c) break;
    bx -= c; ++j;
  }
  const int L = 4096 >> j;
  const int t0 = bx << 7;
  const int tcnt = imin(128, L - t0);
  const int b = blockIdx.y;
  const int z = blockIdx.z;
  const int r = (j - 1) * 4 + b;
  const float* src = (z ? VD : DD) +
      ((size_t)(4 * (4096 - (4096 >> (j - 1))) + b * L)) * CKD;
  float* dre = z ? XVre : XDre;
  float* dim_ = z ? XVim : XDim;

  for (int idx = threadIdx.x; idx < 2048; idx += 256) {
    int ff = idx >> 7, tl = idx & 127;
    int t = t0 + tl;
    int m = (2 * ff * t) & (2 * L - 1);
    float xang = (float)m / (float)L;
    tw[idx] = make_float2(cospif(xang), sinpif(xang));
  }
  __syncthreads();

  float ar[16][2] = {};
  float ai[16][2] = {};
  const float* sp = src + (size_t)t0 * CKD + (threadIdx.x << 1);
  for (int tl = 0; tl < tcnt; ++tl) {
    float2 xv = *(const float2*)sp;
    sp += CKD;
#pragma unroll
    for (int ff = 0; ff < 16; ++ff) {
      float2 cs = tw[(ff << 7) + tl];
      ar[ff][0] += xv.x * cs.x; ar[ff][1] += xv.y * cs.x;
      ai[ff][0] -= xv.x * cs.y; ai[ff][1] -= xv.y * cs.y;
    }
  }
  const int i0 = threadIdx.x << 1;
#pragma unroll
  for (int ff = 0; ff < 16; ++ff) {
    size_t bidx = ((size_t)ff * NROWS + r) * CKD + i0;
    atomicAdd(&dre[bidx], ar[ff][0]);
    atomicAdd(&dre[bidx + 1], ar[ff][1]);
    atomicAdd(&dim_[bidx], ai[ff][0]);
    atomicAdd(&dim_[bidx + 1], ai[ff][1]);
  }
}

// ---------------------------------------------------------------------------
// Weight transpose (i,o,f) -> (f,i,o), one array per launch
// ---------------------------------------------------------------------------
__global__ __launch_bounds__(256) void k_transw(
    const float* __restrict__ src, float* __restrict__ dst)
{
  int g = blockIdx.x * 256 + threadIdx.x;  // 512*512
  int i = g >> 9, o = g & 511;
  const float4* s = (const float4*)(src + (size_t)g * 16);
  float4 a = s[0], b = s[1], c = s[2], d = s[3];
  float v[16] = {a.x, a.y, a.z, a.w, b.x, b.y, b.z, b.w,
                 c.x, c.y, c.z, c.w, d.x, d.y, d.z, d.w};
#pragma unroll
  for (int f = 0; f < 16; ++f)
    dst[(((size_t)f << 9) + i) * CKD + o] = v[f];
}

// ---------------------------------------------------------------------------
// Channel mix per frequency: complex GEMM over 4 rows (one level) x 512 o
// UdF = XD@A + XV@B ; UsF = XD@C.  grid = (f=16, level=11, o-half=2)
// ---------------------------------------------------------------------------
__global__ __launch_bounds__(256) void k_mix(
    const float* __restrict__ XDre, const float* __restrict__ XDim,
    const float* __restrict__ XVre, const float* __restrict__ XVim,
    const float* __restrict__ war, const float* __restrict__ wai,
    const float* __restrict__ wbr, const float* __restrict__ wbi,
    const float* __restrict__ wcr, const float* __restrict__ wci,
    float* __restrict__ UdFre, float* __restrict__ UdFim,
    float* __restrict__ UsFre, float* __restrict__ UsFim,
    int wt_mode)
{
  const int f = blockIdx.x;
  const int jg = blockIdx.y;
  const int j = jg + 1;
  const int L = 4096 >> j;
  const int l = imin(16, (L >> 1) + 1);
  if (f >= l) return;  // iDFT never reads these frequencies for this level
  __shared__ float sx[1024];  // [r][ii][plane]  plane: XDre,XDim,XVre,XVim
  const int r0 = jg << 2;
  const int o = (blockIdx.z << 8) + threadIdx.x;
  const int tid = threadIdx.x;
  const int li = tid & 63, s0 = tid >> 6;
  float udr[4] = {}, udi[4] = {}, usr[4] = {}, usi[4] = {};
  const float* pl[4] = {XDre, XDim, XVre, XVim};
  for (int i0 = 0; i0 < 512; i0 += 64) {
    __syncthreads();
#pragma unroll
    for (int s = 0; s < 4; ++s) {
      int seg = s0 + (s << 2);
      int p = seg >> 2, rr = seg & 3;
      sx[(((rr << 6) + li) << 2) + p] =
          pl[p][((size_t)f * NROWS + r0 + rr) * CKD + i0 + li];
    }
    __syncthreads();
    for (int ii = 0; ii < 64; ++ii) {
      int i = i0 + ii;
      size_t wo = wt_mode ? ((((size_t)f << 9) + i) << 9) + o
                          : ((((size_t)i << 9) + o) << 4) + f;
      float ar_ = war[wo], ai_ = wai[wo];
      float br_ = wbr[wo], bi_ = wbi[wo];
      float cr_ = wcr[wo], ci_ = wci[wo];
#pragma unroll
      for (int rr = 0; rr < 4; ++rr) {
        float4 xv = *(const float4*)&sx[((rr << 6) + ii) << 2];
        udr[rr] += xv.x * ar_ - xv.y * ai_ + xv.z * br_ - xv.w * bi_;
        udi[rr] += xv.x * ai_ + xv.y * ar_ + xv.z * bi_ + xv.w * br_;
        usr[rr] += xv.x * cr_ - xv.y * ci_;
        usi[rr] += xv.x * ci_ + xv.y * cr_;
      }
    }
  }
#pragma unroll
  for (int rr = 0; rr < 4; ++rr) {
    size_t bidx = ((size_t)f * NROWS + r0 + rr) * CKD + o;
    UdFre[bidx] = udr[rr];
    UdFim[bidx] = udi[rr];
    UsFre[bidx] = usr[rr];
    UsFim[bidx] = usi[rr];
  }
}

// ---------------------------------------------------------------------------
// Inverse truncated DFT (irfft with only l frequencies):
// y[t] = (1/L) * sum_{f<l} wgt_f * (Re X cos - Im X sin), wgt = 1 for f=0/Nyquist else 2
// grid.x enumerates (level j, 8-t chunk); grid.y = b. Writes Ud and Us time arenas.
// ---------------------------------------------------------------------------
__global__ __launch_bounds__(256) void k_idft(
    const float* __restrict__ UdFre, const float* __restrict__ UdFim,
    const float* __restrict__ UsFre, const float* __restrict__ UsFim,
    float* __restrict__ UdT, float* __restrict__ UsT)
{
  __shared__ float2 tw[128];  // [f][8]
  int bx = blockIdx.x, j = 1;
  for (;;) {
    int c = (4096 >> j) >> 3; if (c < 1) c = 1;
    if (bx < c) break;
    bx -= c; ++j;
  }
  const int L = 4096 >> j;
  const int l = imin(16, (L >> 1) + 1);
  const int t0 = bx << 3;
  const int b = blockIdx.y;
  const int r = (j - 1) * 4 + b;
  if (threadIdx.x < 128) {
    int ff = threadIdx.x >> 3, tl = threadIdx.x & 7;
    int t = t0 + tl;
    int m = (2 * ff * t) & (2 * L - 1);
    float xang = (float)m / (float)L;
    float wgt = (ff == 0 || 2 * ff == L) ? 1.0f : 2.0f;
    float sc = wgt / (float)L;
    tw[threadIdx.x] = make_float2(cospif(xang) * sc, sinpif(xang) * sc);
  }
  __syncthreads();
  const int o = threadIdx.x << 1;
  float2 ud[8], us[8];
#pragma unroll
  for (int tl = 0; tl < 8; ++tl) { ud[tl] = make_float2(0.f, 0.f); us[tl] = make_float2(0.f, 0.f); }
  for (int ff = 0; ff < l; ++ff) {
    size_t bidx = ((size_t)ff * NROWS + r) * CKD + o;
    float2 er = *(const float2*)(UdFre + bidx);
    float2 ei = *(const float2*)(UdFim + bidx);
    float2 sr = *(const float2*)(UsFre + bidx);
    float2 si = *(const float2*)(UsFim + bidx);
#pragma unroll
    for (int tl = 0; tl < 8; ++tl) {
      float2 cs = tw[(ff << 3) + tl];
      ud[tl].x += er.x * cs.x - ei.x * cs.y;
      ud[tl].y += er.y * cs.x - ei.y * cs.y;
      us[tl].x += sr.x * cs.x - si.x * cs.y;
      us[tl].y += sr.y * cs.x - si.y * cs.y;
    }
  }
  int tmax = imin(8, L - t0);
  size_t obase = ((size_t)(4 * (4096 - (4096 >> (j - 1))) + b * L + t0)) * CKD + o;
  for (int tl = 0; tl < tmax; ++tl) {
    *(float2*)(UdT + obase + (size_t)tl * CKD) = ud[tl];
    *(float2*)(UsT + obase + (size_t)tl * CKD) = us[tl];
  }
}

// ---------------------------------------------------------------------------
// Reconstruction step: a = [v + Us, Ud]; xe = a@rc_e, xo = a@rc_o, interleave
// ---------------------------------------------------------------------------
__global__ __launch_bounds__(256) void k_recon(
    const float* __restrict__ Vcur, const float* __restrict__ UdT,
    const float* __restrict__ UsT, const float* __restrict__ rc_e,
    const float* __restrict__ rc_o, float* __restrict__ Vnext,
    int Lc, int abase)
{
  __shared__ float Re[128], Ro[128];
  if (threadIdx.x < 128) Re[threadIdx.x] = rc_e[threadIdx.x];
  else Ro[threadIdx.x - 128] = rc_o[threadIdx.x - 128];
  __syncthreads();
  int g = blockIdx.x * 256 + threadIdx.x;
  if (g >= 4 * Lc * 64) return;
  int c = g & 63;
  int s = (g >> 6) % Lc;
  int b = g / (Lc << 6);
  size_t vrow = ((size_t)b * Lc + s) * CKD + (c << 3);
  size_t arow = ((size_t)abase + (size_t)b * Lc + s) * CKD + (c << 3);
  float a[16];
  {
    float4 t0_ = *(const float4*)(Vcur + vrow);
    float4 t1_ = *(const float4*)(Vcur + vrow + 4);
    float4 u0 = *(const float4*)(UsT + arow);
    float4 u1 = *(const float4*)(UsT + arow + 4);
    a[0]=t0_.x+u0.x; a[1]=t0_.y+u0.y; a[2]=t0_.z+u0.z; a[3]=t0_.w+u0.w;
    a[4]=t1_.x+u1.x; a[5]=t1_.y+u1.y; a[6]=t1_.z+u1.z; a[7]=t1_.w+u1.w;
    float4 d0 = *(const float4*)(UdT + arow);
    float4 d1 = *(const float4*)(UdT + arow + 4);
    a[8]=d0.x; a[9]=d0.y; a[10]=d0.z; a[11]=d0.w;
    a[12]=d1.x; a[13]=d1.y; a[14]=d1.z; a[15]=d1.w;
  }
  float xe[8] = {}, xo[8] = {};
#pragma unroll
  for (int m = 0; m < 16; ++m)
#pragma unroll
    for (int k = 0; k < 8; ++k) {
      xe[k] += a[m] * Re[m * 8 + k];
      xo[k] += a[m] * Ro[m * 8 + k];
    }
  size_t orow = ((size_t)b * (Lc << 1) + (s << 1)) * CKD + (c << 3);
  *(float4*)(Vnext + orow)           = make_float4(xe[0], xe[1], xe[2], xe[3]);
  *(float4*)(Vnext + orow + 4)       = make_float4(xe[4], xe[5], xe[6], xe[7]);
  *(float4*)(Vnext + orow + CKD)     = make_float4(xo[0], xo[1], xo[2], xo[3]);
  *(float4*)(Vnext + orow + CKD + 4) = make_float4(xo[4], xo[5], xo[6], xo[7]);
}

// ---------------------------------------------------------------------------
extern "C" void kernel_launch(void* const* d_in, const int* in_sizes, int n_in,
                              void* d_out, int out_size, void* d_ws, size_t ws_size,
                              hipStream_t stream)
{
  const float* x     = (const float*)d_in[0];
  const float* Lk0_w = (const float*)d_in[1];
  const float* Lk0_b = (const float*)d_in[2];
  const float* Lk1_w = (const float*)d_in[3];
  const float* Lk1_b = (const float*)d_in[4];
  const float* T0_w  = (const float*)d_in[5];
  const float* T0_b  = (const float*)d_in[6];
  const float* Ar = (const float*)d_in[7];
  const float* Ai = (const float*)d_in[8];
  const float* Br = (const float*)d_in[9];
  const float* Bi = (const float*)d_in[10];
  const float* Cr = (const float*)d_in[11];
  const float* Ci = (const float*)d_in[12];
  const float* ec_s = (const float*)d_in[13];
  const float* ec_d = (const float*)d_in[14];
  const float* rc_e = (const float*)d_in[15];
  const float* rc_o = (const float*)d_in[16];
  float* out = (float*)d_out;

  // workspace layout (floats)
  float* w = (float*)d_ws;
  float* V0 = w;   w += (size_t)4 * 4096 * 512;  // 8,388,608  (aliased as recon A)
  float* VD = w;   w += (size_t)4 * 4094 * 512;  // 8,380,416  (aliased as UsT)
  float* DD = w;   w += (size_t)4 * 4094 * 512;  // 8,380,416  (aliased as UdT)
  float* RB = w;   w += (size_t)4 * 4096 * 512;  // 8,388,608
  float* XDre = w; w += 360448;
  float* XDim = w; w += 360448;
  float* XVre = w; w += 360448;
  float* XVim = w; w += 360448;
  float* UdFre = w; w += 360448;
  float* UdFim = w; w += 360448;
  float* UsFre = w; w += 360448;
  float* UsFim = w; w += 360448;
  float* WT = w;  // 6 * 4,194,304 if it fits
  float* RA = V0;
  float* UdT = DD;
  float* UsT = VD;

  const size_t BASE_FLOATS = 36421632ull;
  const size_t WT_FLOATS   = 25165824ull;
  if (ws_size < BASE_FLOATS * 4) return;  // cannot run
  const bool use_wt = ws_size >= (BASE_FLOATS + WT_FLOATS) * 4;

  // 1. Lk0 GEMM (+ wraparound pad to 4096)
  k_gemm512<<<dim3(256, 8), dim3(256), 0, stream>>>(x, Lk0_w, Lk0_b, V0, 0);

  // 2. decomposition levels j = 1..11
  for (int j = 1; j <= 11; ++j) {
    int Lout = 4096 >> j;
    int pin = 4096 >> (j - 1);
    const float* vin = (j == 1)
        ? V0
        : VD + (size_t)4 * (4096 - (4096 >> (j - 2))) * 512;
    size_t base = (size_t)4 * (4096 - (4096 >> (j - 1))) * 512;
    k_decomp<<<dim3(Lout), dim3(256), 0, stream>>>(vin, ec_s, ec_d,
                                                   DD + base, VD + base, Lout, pin);
  }

  // 3. T0 on v_11 (before UsT aliases over VD)
  k_t0<<<dim3(2), dim3(256), 0, stream>>>(VD + (size_t)4 * 4092 * 512, T0_w, T0_b, RA);

  // 4. zero X accumulators (XDre..XVim contiguous)
  hipMemsetAsync(XDre, 0, (size_t)4 * 360448 * 4, stream);

  // 5. optional weight transpose (i,o,f) -> (f,i,o)
  if (use_wt) {
    const float* srcs[6] = {Ar, Ai, Br, Bi, Cr, Ci};
    for (int p = 0; p < 6; ++p)
      k_transw<<<dim3(1024), dim3(256), 0, stream>>>(srcs[p], WT + (size_t)p * 4194304);
  }

  // 6. forward DFTs of all levels (d and v arenas)
  k_fdft<<<dim3(37, 4, 2), dim3(256), 0, stream>>>(DD, VD, XDre, XDim, XVre, XVim);

  // 7. per-frequency channel mix
  const float* m0 = use_wt ? WT + 0ull * 4194304 : Ar;
  const float* m1 = use_wt ? WT + 1ull * 4194304 : Ai;
  const float* m2 = use_wt ? WT + 2ull * 4194304 : Br;
  const float* m3 = use_wt ? WT + 3ull * 4194304 : Bi;
  const float* m4 = use_wt ? WT + 4ull * 4194304 : Cr;
  const float* m5 = use_wt ? WT + 5ull * 4194304 : Ci;
  k_mix<<<dim3(16, 11, 2), dim3(256), 0, stream>>>(
      XDre, XDim, XVre, XVim, m0, m1, m2, m3, m4, m5,
      UdFre, UdFim, UsFre, UsFim, use_wt ? 1 : 0);

  // 8. inverse DFTs into time-domain Ud/Us arenas (alias DD/VD)
  k_idft<<<dim3(513, 4), dim3(256), 0, stream>>>(UdFre, UdFim, UsFre, UsFim, UdT, UsT);

  // 9. reconstruction j = 11..1 (ping-pong RA/RB)
  float* cur = RA;
  float* nxt = RB;
  for (int j = 11; j >= 1; --j) {
    int Lc = 4096 >> j;
    int abase = 4 * (4096 - (4096 >> (j - 1)));
    k_recon<<<dim3(Lc), dim3(256), 0, stream>>>(cur, UdT, UsT, rc_e, rc_o, nxt, Lc, abase);
    float* t = cur; cur = nxt; nxt = t;
  }

  // 10. Lk1 GEMM on first 3072 rows of final buffer (pitch 4096)
  k_gemm512<<<dim3(192, 8), dim3(256), 0, stream>>>(cur, Lk1_w, Lk1_b, out, 1);
}

// Round 2
// 780.279 us; speedup vs baseline: 1.1595x; 1.1595x over previous
//
#include <hip/hip_runtime.h>

#define CKD 512
#define NROWS 44
#define XPLANE 360448  // 16*44*512

static __device__ __forceinline__ int imin(int a, int b) { return a < b ? a : b; }

// ---------------------------------------------------------------------------
// GEMM: Out[m][n] = sum_k A[row(m)][k] * W[n][k] + bias[n]   (K = N = 512)
// mode 0: Lk0, M = 4*4096, source row wraps (t >= 3072 -> t-3072), out pitch 4096/b
// mode 1: Lk1, M = 4*3072, source rows from pitch-4096 buffer
// ---------------------------------------------------------------------------
__global__ __launch_bounds__(256) void k_gemm512(
    const float* __restrict__ A, const float* __restrict__ W,
    const float* __restrict__ bias, float* __restrict__ Out, int mode)
{
  __shared__ float As[16][68];
  __shared__ float Ws[16][68];
  const int tid = threadIdx.x;
  const int lr = tid >> 2;           // 0..63 row within tile
  const int lk = (tid & 3) << 2;     // 0,4,8,12
  const int tm = tid >> 4, tn = tid & 15;

  int gm = (blockIdx.x << 6) + lr;
  int arow;
  if (mode == 0) {
    int b = gm >> 12;
    int t = gm & 4095;
    if (t >= 3072) t -= 3072;
    arow = b * 3072 + t;
  } else {
    int b = gm / 3072;
    int t = gm - b * 3072;
    arow = (b << 12) + t;
  }
  const float* Ap = A + (size_t)arow * CKD;
  const float* Wp = W + (size_t)((blockIdx.y << 6) + lr) * CKD;

  float acc[4][4] = {};
  for (int k0 = 0; k0 < CKD; k0 += 16) {
    float4 av = *(const float4*)(Ap + k0 + lk);
    float4 wv = *(const float4*)(Wp + k0 + lk);
    __syncthreads();
    As[lk + 0][lr] = av.x; As[lk + 1][lr] = av.y; As[lk + 2][lr] = av.z; As[lk + 3][lr] = av.w;
    Ws[lk + 0][lr] = wv.x; Ws[lk + 1][lr] = wv.y; Ws[lk + 2][lr] = wv.z; Ws[lk + 3][lr] = wv.w;
    __syncthreads();
#pragma unroll
    for (int kk = 0; kk < 16; ++kk) {
      float4 a4 = *(const float4*)&As[kk][tm << 2];
      float4 w4 = *(const float4*)&Ws[kk][tn << 2];
      float aa[4] = {a4.x, a4.y, a4.z, a4.w};
      float ww[4] = {w4.x, w4.y, w4.z, w4.w};
#pragma unroll
      for (int ii = 0; ii < 4; ++ii)
#pragma unroll
        for (int jj = 0; jj < 4; ++jj) acc[ii][jj] += aa[ii] * ww[jj];
    }
  }
  const int om = (blockIdx.x << 6) + (tm << 2);
  const int on = (blockIdx.y << 6) + (tn << 2);
  float4 b4 = *(const float4*)(bias + on);
#pragma unroll
  for (int ii = 0; ii < 4; ++ii) {
    float4 r;
    r.x = acc[ii][0] + b4.x; r.y = acc[ii][1] + b4.y;
    r.z = acc[ii][2] + b4.z; r.w = acc[ii][3] + b4.w;
    *(float4*)(Out + (size_t)(om + ii) * CKD + on) = r;
  }
}

// ---------------------------------------------------------------------------
// Decomposition step: xa = [v[2s], v[2s+1]] (16), d = xa@ec_d, v' = xa@ec_s
// ---------------------------------------------------------------------------
__global__ __launch_bounds__(256) void k_decomp(
    const float* __restrict__ Vin, const float* __restrict__ ec_s,
    const float* __restrict__ ec_d, float* __restrict__ Dout,
    float* __restrict__ Vout, int Lout, int pin)
{
  __shared__ float Es[128], Ed[128];
  if (threadIdx.x < 128) Es[threadIdx.x] = ec_s[threadIdx.x];
  else Ed[threadIdx.x - 128] = ec_d[threadIdx.x - 128];
  __syncthreads();
  int g = blockIdx.x * 256 + threadIdx.x;
  if (g >= 4 * Lout * 64) return;
  int c = g & 63;
  int s = (g >> 6) % Lout;
  int b = g / (Lout << 6);
  const float* r0 = Vin + ((size_t)b * pin + 2 * s) * CKD + (c << 3);
  float a[16];
  float4 v0 = *(const float4*)r0;
  float4 v1 = *(const float4*)(r0 + 4);
  float4 v2 = *(const float4*)(r0 + CKD);
  float4 v3 = *(const float4*)(r0 + CKD + 4);
  a[0]=v0.x; a[1]=v0.y; a[2]=v0.z; a[3]=v0.w; a[4]=v1.x; a[5]=v1.y; a[6]=v1.z; a[7]=v1.w;
  a[8]=v2.x; a[9]=v2.y; a[10]=v2.z; a[11]=v2.w; a[12]=v3.x; a[13]=v3.y; a[14]=v3.z; a[15]=v3.w;
  float dv[8] = {}, vv[8] = {};
#pragma unroll
  for (int m = 0; m < 16; ++m)
#pragma unroll
    for (int k = 0; k < 8; ++k) {
      dv[k] += a[m] * Ed[m * 8 + k];
      vv[k] += a[m] * Es[m * 8 + k];
    }
  size_t orow = ((size_t)b * Lout + s) * CKD + (c << 3);
  *(float4*)(Dout + orow)     = make_float4(dv[0], dv[1], dv[2], dv[3]);
  *(float4*)(Dout + orow + 4) = make_float4(dv[4], dv[5], dv[6], dv[7]);
  *(float4*)(Vout + orow)     = make_float4(vv[0], vv[1], vv[2], vv[3]);
  *(float4*)(Vout + orow + 4) = make_float4(vv[4], vv[5], vv[6], vv[7]);
}

// ---------------------------------------------------------------------------
// T0
// ---------------------------------------------------------------------------
__global__ __launch_bounds__(256) void k_t0(
    const float* __restrict__ Vin, const float* __restrict__ T0w,
    const float* __restrict__ T0b, float* __restrict__ Out)
{
  int g = blockIdx.x * 256 + threadIdx.x;
  if (g >= 4 * 2 * 64) return;
  int c = g & 63;
  int t = (g >> 6) & 1;
  int b = g >> 7;
  const float* src = Vin + ((size_t)(b * 2 + t)) * CKD + (c << 3);
  float a[8];
  float4 v0 = *(const float4*)src;
  float4 v1 = *(const float4*)(src + 4);
  a[0]=v0.x; a[1]=v0.y; a[2]=v0.z; a[3]=v0.w; a[4]=v1.x; a[5]=v1.y; a[6]=v1.z; a[7]=v1.w;
  float o[8];
#pragma unroll
  for (int ko = 0; ko < 8; ++ko) {
    float sum = T0b[ko];
#pragma unroll
    for (int k = 0; k < 8; ++k) sum += a[k] * T0w[ko * 8 + k];
    o[ko] = sum;
  }
  float* dst = Out + ((size_t)(b * 2 + t)) * CKD + (c << 3);
  *(float4*)dst       = make_float4(o[0], o[1], o[2], o[3]);
  *(float4*)(dst + 4) = make_float4(o[4], o[5], o[6], o[7]);
}

// ---------------------------------------------------------------------------
// Forward truncated DFT (atomic accumulate over t-chunks)
// ---------------------------------------------------------------------------
__global__ __launch_bounds__(256) void k_fdft(
    const float* __restrict__ DD, const float* __restrict__ VD,
    float* __restrict__ XDre, float* __restrict__ XDim,
    float* __restrict__ XVre, float* __restrict__ XVim)
{
  __shared__ float2 tw[2048];  // [f][128]
  int bx = blockIdx.x, j = 1;
  for (;;) {
    int c = (4096 >> j) >> 7; if (c < 1) c = 1;
    if (bx < c) break;
    bx -= c; ++j;
  }
  const int L = 4096 >> j;
  const int t0 = bx << 7;
  const int tcnt = imin(128, L - t0);
  const int b = blockIdx.y;
  const int z = blockIdx.z;
  const int r = (j - 1) * 4 + b;
  const float* src = (z ? VD : DD) +
      ((size_t)(4 * (4096 - (4096 >> (j - 1))) + b * L)) * CKD;
  float* dre = z ? XVre : XDre;
  float* dim_ = z ? XVim : XDim;

  for (int idx = threadIdx.x; idx < 2048; idx += 256) {
    int ff = idx >> 7, tl = idx & 127;
    int t = t0 + tl;
    int m = (2 * ff * t) & (2 * L - 1);
    float xang = (float)m / (float)L;
    tw[idx] = make_float2(cospif(xang), sinpif(xang));
  }
  __syncthreads();

  float ar[16][2] = {};
  float ai[16][2] = {};
  const float* sp = src + (size_t)t0 * CKD + (threadIdx.x << 1);
  for (int tl = 0; tl < tcnt; ++tl) {
    float2 xv = *(const float2*)sp;
    sp += CKD;
#pragma unroll
    for (int ff = 0; ff < 16; ++ff) {
      float2 cs = tw[(ff << 7) + tl];
      ar[ff][0] += xv.x * cs.x; ar[ff][1] += xv.y * cs.x;
      ai[ff][0] -= xv.x * cs.y; ai[ff][1] -= xv.y * cs.y;
    }
  }
  const int i0 = threadIdx.x << 1;
#pragma unroll
  for (int ff = 0; ff < 16; ++ff) {
    size_t bidx = ((size_t)ff * NROWS + r) * CKD + i0;
    atomicAdd(&dre[bidx], ar[ff][0]);
    atomicAdd(&dre[bidx + 1], ar[ff][1]);
    atomicAdd(&dim_[bidx], ai[ff][0]);
    atomicAdd(&dim_[bidx + 1], ai[ff][1]);
  }
}

// ---------------------------------------------------------------------------
// Fused weight repack: (i,o,f) x6 -> W4[f][i][o] = (Ar,Ai,Br,Bi) float4
//                                   W2[f][i][o] = (Cr,Ci) float2
// ---------------------------------------------------------------------------
__global__ __launch_bounds__(256) void k_transw6(
    const float* __restrict__ sAr, const float* __restrict__ sAi,
    const float* __restrict__ sBr, const float* __restrict__ sBi,
    const float* __restrict__ sCr, const float* __restrict__ sCi,
    float* __restrict__ W4, float* __restrict__ W2)
{
  int g = blockIdx.x * 256 + threadIdx.x;  // i*512 + o
  float ar[16], ai[16], br[16], bi[16], cr[16], ci[16];
  const size_t sb = (size_t)g * 16;
#pragma unroll
  for (int q = 0; q < 4; ++q) {
    float4 t;
    t = *(const float4*)(sAr + sb + q * 4); ar[q*4]=t.x; ar[q*4+1]=t.y; ar[q*4+2]=t.z; ar[q*4+3]=t.w;
    t = *(const float4*)(sAi + sb + q * 4); ai[q*4]=t.x; ai[q*4+1]=t.y; ai[q*4+2]=t.z; ai[q*4+3]=t.w;
    t = *(const float4*)(sBr + sb + q * 4); br[q*4]=t.x; br[q*4+1]=t.y; br[q*4+2]=t.z; br[q*4+3]=t.w;
    t = *(const float4*)(sBi + sb + q * 4); bi[q*4]=t.x; bi[q*4+1]=t.y; bi[q*4+2]=t.z; bi[q*4+3]=t.w;
    t = *(const float4*)(sCr + sb + q * 4); cr[q*4]=t.x; cr[q*4+1]=t.y; cr[q*4+2]=t.z; cr[q*4+3]=t.w;
    t = *(const float4*)(sCi + sb + q * 4); ci[q*4]=t.x; ci[q*4+1]=t.y; ci[q*4+2]=t.z; ci[q*4+3]=t.w;
  }
#pragma unroll
  for (int f = 0; f < 16; ++f) {
    size_t e = ((size_t)f << 18) + g;  // f*262144 + i*512 + o
    *(float4*)(W4 + (e << 2)) = make_float4(ar[f], ai[f], br[f], bi[f]);
    *(float2*)(W2 + (e << 1)) = make_float2(cr[f], ci[f]);
  }
}

// ---------------------------------------------------------------------------
// Channel mix v2: per (f, o-tile of 128, K-chunk of 128) block, ALL 44 rows.
// 512 threads = 64 o-lanes x 8 row-groups (6/6/6/6/5/5/5/5 rows).
// Each thread covers o and o+64. Partials -> Part[kc][arr][f*44+r][o].
// ---------------------------------------------------------------------------
__global__ __launch_bounds__(512) void k_mix2(
    const float* __restrict__ XDre, const float* __restrict__ XDim,
    const float* __restrict__ XVre, const float* __restrict__ XVim,
    const float* __restrict__ W4, const float* __restrict__ W2,
    const float* __restrict__ war, const float* __restrict__ wai,
    const float* __restrict__ wbr, const float* __restrict__ wbi,
    const float* __restrict__ wcr, const float* __restrict__ wci,
    float* __restrict__ Part, int wt_mode)
{
  const int f = blockIdx.x;
  const int ot = blockIdx.y;   // 0..3
  const int kc = blockIdx.z;   // 0..3
  const int lane = threadIdx.x & 63;
  const int rg = threadIdx.x >> 6;           // 0..7
  const int rbase = (rg < 4) ? rg * 6 : 24 + (rg - 4) * 5;
  const int rcnt = (rg < 4) ? 6 : 5;
  const int o0 = (ot << 7) + lane;           // covers o0 and o0+64

  __shared__ float4 sx[NROWS * 64];          // [r][i-local], 45 KiB

  float udr[6][2] = {}, udi[6][2] = {}, usr[6][2] = {}, usi[6][2] = {};

  for (int st = 0; st < 2; ++st) {
    const int i0 = (kc << 7) + (st << 6);
    __syncthreads();
    for (int idx = threadIdx.x; idx < NROWS * 64; idx += 512) {
      int r = idx >> 6, il = idx & 63;
      size_t xb = ((size_t)f * NROWS + r) * CKD + i0 + il;
      sx[idx] = make_float4(XDre[xb], XDim[xb], XVre[xb], XVim[xb]);
    }
    __syncthreads();
    for (int ii = 0; ii < 64; ++ii) {
      const int i = i0 + ii;
      float4 wa0, wa1; float2 wc0, wc1;
      if (wt_mode) {
        size_t e = (((size_t)f << 9) + i) << 9;  // (f*512 + i)*512
        wa0 = *(const float4*)(W4 + ((e + o0) << 2));
        wa1 = *(const float4*)(W4 + ((e + o0 + 64) << 2));
        wc0 = *(const float2*)(W2 + ((e + o0) << 1));
        wc1 = *(const float2*)(W2 + ((e + o0 + 64) << 1));
      } else {
        size_t wo = ((((size_t)i << 9) + o0) << 4) + f;
        wa0 = make_float4(war[wo], wai[wo], wbr[wo], wbi[wo]);
        wc0 = make_float2(wcr[wo], wci[wo]);
        size_t w1 = wo + (64u << 4);
        wa1 = make_float4(war[w1], wai[w1], wbr[w1], wbi[w1]);
        wc1 = make_float2(wcr[w1], wci[w1]);
      }
#pragma unroll
      for (int rr = 0; rr < 6; ++rr) {
        if (rr < rcnt) {
          float4 xv = sx[((rbase + rr) << 6) + ii];
          udr[rr][0] += xv.x * wa0.x - xv.y * wa0.y + xv.z * wa0.z - xv.w * wa0.w;
          udi[rr][0] += xv.x * wa0.y + xv.y * wa0.x + xv.z * wa0.w + xv.w * wa0.z;
          usr[rr][0] += xv.x * wc0.x - xv.y * wc0.y;
          usi[rr][0] += xv.x * wc0.y + xv.y * wc0.x;
          udr[rr][1] += xv.x * wa1.x - xv.y * wa1.y + xv.z * wa1.z - xv.w * wa1.w;
          udi[rr][1] += xv.x * wa1.y + xv.y * wa1.x + xv.z * wa1.w + xv.w * wa1.z;
          usr[rr][1] += xv.x * wc1.x - xv.y * wc1.y;
          usi[rr][1] += xv.x * wc1.y + xv.y * wc1.x;
        }
      }
    }
  }

  const size_t kb = (size_t)kc * 4 * XPLANE;
#pragma unroll
  for (int rr = 0; rr < 6; ++rr) {
    if (rr < rcnt) {
      size_t rb_ = ((size_t)f * NROWS + rbase + rr) * CKD;
      Part[kb + 0 * XPLANE + rb_ + o0]      = udr[rr][0];
      Part[kb + 1 * XPLANE + rb_ + o0]      = udi[rr][0];
      Part[kb + 2 * XPLANE + rb_ + o0]      = usr[rr][0];
      Part[kb + 3 * XPLANE + rb_ + o0]      = usi[rr][0];
      Part[kb + 0 * XPLANE + rb_ + o0 + 64] = udr[rr][1];
      Part[kb + 1 * XPLANE + rb_ + o0 + 64] = udi[rr][1];
      Part[kb + 2 * XPLANE + rb_ + o0 + 64] = usr[rr][1];
      Part[kb + 3 * XPLANE + rb_ + o0 + 64] = usi[rr][1];
    }
  }
}

// ---------------------------------------------------------------------------
// Reduce 4 K-chunk partials -> final spectral UdF/UsF arrays
// ---------------------------------------------------------------------------
__global__ __launch_bounds__(256) void k_reduce(
    const float* __restrict__ Part,
    float* __restrict__ UdFre, float* __restrict__ UdFim,
    float* __restrict__ UsFre, float* __restrict__ UsFim)
{
  int idx = blockIdx.x * 256 + threadIdx.x;
  if (idx >= XPLANE) return;
  float s0 = 0.f, s1 = 0.f, s2 = 0.f, s3 = 0.f;
#pragma unroll
  for (int kc = 0; kc < 4; ++kc) {
    const float* p = Part + (size_t)kc * 4 * XPLANE;
    s0 += p[0 * XPLANE + idx];
    s1 += p[1 * XPLANE + idx];
    s2 += p[2 * XPLANE + idx];
    s3 += p[3 * XPLANE + idx];
  }
  UdFre[idx] = s0; UdFim[idx] = s1; UsFre[idx] = s2; UsFim[idx] = s3;
}

// ---------------------------------------------------------------------------
// Inverse truncated DFT
// ---------------------------------------------------------------------------
__global__ __launch_bounds__(256) void k_idft(
    const float* __restrict__ UdFre, const float* __restrict__ UdFim,
    const float* __restrict__ UsFre, const float* __restrict__ UsFim,
    float* __restrict__ UdT, float* __restrict__ UsT)
{
  __shared__ float2 tw[128];  // [f][8]
  int bx = blockIdx.x, j = 1;
  for (;;) {
    int c = (4096 >> j) >> 3; if (c < 1) c = 1;
    if (bx < c) break;
    bx -= c; ++j;
  }
  const int L = 4096 >> j;
  const int l = imin(16, (L >> 1) + 1);
  const int t0 = bx << 3;
  const int b = blockIdx.y;
  const int r = (j - 1) * 4 + b;
  if (threadIdx.x < 128) {
    int ff = threadIdx.x >> 3, tl = threadIdx.x & 7;
    int t = t0 + tl;
    int m = (2 * ff * t) & (2 * L - 1);
    float xang = (float)m / (float)L;
    float wgt = (ff == 0 || 2 * ff == L) ? 1.0f : 2.0f;
    float sc = wgt / (float)L;
    tw[threadIdx.x] = make_float2(cospif(xang) * sc, sinpif(xang) * sc);
  }
  __syncthreads();
  const int o = threadIdx.x << 1;
  float2 ud[8], us[8];
#pragma unroll
  for (int tl = 0; tl < 8; ++tl) { ud[tl] = make_float2(0.f, 0.f); us[tl] = make_float2(0.f, 0.f); }
  for (int ff = 0; ff < l; ++ff) {
    size_t bidx = ((size_t)ff * NROWS + r) * CKD + o;
    float2 er = *(const float2*)(UdFre + bidx);
    float2 ei = *(const float2*)(UdFim + bidx);
    float2 sr = *(const float2*)(UsFre + bidx);
    float2 si = *(const float2*)(UsFim + bidx);
#pragma unroll
    for (int tl = 0; tl < 8; ++tl) {
      float2 cs = tw[(ff << 3) + tl];
      ud[tl].x += er.x * cs.x - ei.x * cs.y;
      ud[tl].y += er.y * cs.x - ei.y * cs.y;
      us[tl].x += sr.x * cs.x - si.x * cs.y;
      us[tl].y += sr.y * cs.x - si.y * cs.y;
    }
  }
  int tmax = imin(8, L - t0);
  size_t obase = ((size_t)(4 * (4096 - (4096 >> (j - 1))) + b * L + t0)) * CKD + o;
  for (int tl = 0; tl < tmax; ++tl) {
    *(float2*)(UdT + obase + (size_t)tl * CKD) = ud[tl];
    *(float2*)(UsT + obase + (size_t)tl * CKD) = us[tl];
  }
}

// ---------------------------------------------------------------------------
// Reconstruction
// ---------------------------------------------------------------------------
__global__ __launch_bounds__(256) void k_recon(
    const float* __restrict__ Vcur, const float* __restrict__ UdT,
    const float* __restrict__ UsT, const float* __restrict__ rc_e,
    const float* __restrict__ rc_o, float* __restrict__ Vnext,
    int Lc, int abase)
{
  __shared__ float Re[128], Ro[128];
  if (threadIdx.x < 128) Re[threadIdx.x] = rc_e[threadIdx.x];
  else Ro[threadIdx.x - 128] = rc_o[threadIdx.x - 128];
  __syncthreads();
  int g = blockIdx.x * 256 + threadIdx.x;
  if (g >= 4 * Lc * 64) return;
  int c = g & 63;
  int s = (g >> 6) % Lc;
  int b = g / (Lc << 6);
  size_t vrow = ((size_t)b * Lc + s) * CKD + (c << 3);
  size_t arow = ((size_t)abase + (size_t)b * Lc + s) * CKD + (c << 3);
  float a[16];
  {
    float4 t0_ = *(const float4*)(Vcur + vrow);
    float4 t1_ = *(const float4*)(Vcur + vrow + 4);
    float4 u0 = *(const float4*)(UsT + arow);
    float4 u1 = *(const float4*)(UsT + arow + 4);
    a[0]=t0_.x+u0.x; a[1]=t0_.y+u0.y; a[2]=t0_.z+u0.z; a[3]=t0_.w+u0.w;
    a[4]=t1_.x+u1.x; a[5]=t1_.y+u1.y; a[6]=t1_.z+u1.z; a[7]=t1_.w+u1.w;
    float4 d0 = *(const float4*)(UdT + arow);
    float4 d1 = *(const float4*)(UdT + arow + 4);
    a[8]=d0.x; a[9]=d0.y; a[10]=d0.z; a[11]=d0.w;
    a[12]=d1.x; a[13]=d1.y; a[14]=d1.z; a[15]=d1.w;
  }
  float xe[8] = {}, xo[8] = {};
#pragma unroll
  for (int m = 0; m < 16; ++m)
#pragma unroll
    for (int k = 0; k < 8; ++k) {
      xe[k] += a[m] * Re[m * 8 + k];
      xo[k] += a[m] * Ro[m * 8 + k];
    }
  size_t orow = ((size_t)b * (Lc << 1) + (s << 1)) * CKD + (c << 3);
  *(float4*)(Vnext + orow)           = make_float4(xe[0], xe[1], xe[2], xe[3]);
  *(float4*)(Vnext + orow + 4)       = make_float4(xe[4], xe[5], xe[6], xe[7]);
  *(float4*)(Vnext + orow + CKD)     = make_float4(xo[0], xo[1], xo[2], xo[3]);
  *(float4*)(Vnext + orow + CKD + 4) = make_float4(xo[4], xo[5], xo[6], xo[7]);
}

// ---------------------------------------------------------------------------
extern "C" void kernel_launch(void* const* d_in, const int* in_sizes, int n_in,
                              void* d_out, int out_size, void* d_ws, size_t ws_size,
                              hipStream_t stream)
{
  const float* x     = (const float*)d_in[0];
  const float* Lk0_w = (const float*)d_in[1];
  const float* Lk0_b = (const float*)d_in[2];
  const float* Lk1_w = (const float*)d_in[3];
  const float* Lk1_b = (const float*)d_in[4];
  const float* T0_w  = (const float*)d_in[5];
  const float* T0_b  = (const float*)d_in[6];
  const float* Ar = (const float*)d_in[7];
  const float* Ai = (const float*)d_in[8];
  const float* Br = (const float*)d_in[9];
  const float* Bi = (const float*)d_in[10];
  const float* Cr = (const float*)d_in[11];
  const float* Ci = (const float*)d_in[12];
  const float* ec_s = (const float*)d_in[13];
  const float* ec_d = (const float*)d_in[14];
  const float* rc_e = (const float*)d_in[15];
  const float* rc_o = (const float*)d_in[16];
  float* out = (float*)d_out;

  // workspace layout (floats)
  float* w = (float*)d_ws;
  float* V0 = w;   w += (size_t)4 * 4096 * 512;  // 8,388,608  (aliased as recon A)
  float* VD = w;   w += (size_t)4 * 4094 * 512;  // 8,380,416  (aliased as UsT)
  float* DD = w;   w += (size_t)4 * 4094 * 512;  // 8,380,416  (aliased as UdT)
  float* RB = w;   w += (size_t)4 * 4096 * 512;  // 8,388,608  (aliased as mix Part)
  float* XDre = w; w += XPLANE;
  float* XDim = w; w += XPLANE;
  float* XVre = w; w += XPLANE;
  float* XVim = w; w += XPLANE;
  float* UdFre = w; w += XPLANE;
  float* UdFim = w; w += XPLANE;
  float* UsFre = w; w += XPLANE;
  float* UsFim = w; w += XPLANE;
  float* WT = w;  // W4 (16.78M) + W2 (8.39M) if it fits
  float* RA = V0;
  float* UdT = DD;
  float* UsT = VD;
  float* Part = RB;   // 16*XPLANE = 5,767,168 <= 8,388,608

  const size_t BASE_FLOATS = 36421632ull;
  const size_t WT_FLOATS   = 25165824ull;
  if (ws_size < BASE_FLOATS * 4) return;  // cannot run
  const bool use_wt = ws_size >= (BASE_FLOATS + WT_FLOATS) * 4;
  float* W4 = WT;
  float* W2 = WT + 16777216ull;

  // 1. Lk0 GEMM (+ wraparound pad to 4096)
  k_gemm512<<<dim3(256, 8), dim3(256), 0, stream>>>(x, Lk0_w, Lk0_b, V0, 0);

  // 2. decomposition levels j = 1..11
  for (int j = 1; j <= 11; ++j) {
    int Lout = 4096 >> j;
    int pin = 4096 >> (j - 1);
    const float* vin = (j == 1)
        ? V0
        : VD + (size_t)4 * (4096 - (4096 >> (j - 2))) * 512;
    size_t base = (size_t)4 * (4096 - (4096 >> (j - 1))) * 512;
    k_decomp<<<dim3(Lout), dim3(256), 0, stream>>>(vin, ec_s, ec_d,
                                                   DD + base, VD + base, Lout, pin);
  }

  // 3. T0 on v_11 (before UsT aliases over VD)
  k_t0<<<dim3(2), dim3(256), 0, stream>>>(VD + (size_t)4 * 4092 * 512, T0_w, T0_b, RA);

  // 4. zero X accumulators (XDre..XVim contiguous)
  hipMemsetAsync(XDre, 0, (size_t)4 * XPLANE * 4, stream);

  // 5. weight repack (i,o,f) -> interleaved [f][i][o] float4/float2
  if (use_wt)
    k_transw6<<<dim3(1024), dim3(256), 0, stream>>>(Ar, Ai, Br, Bi, Cr, Ci, W4, W2);

  // 6. forward DFTs of all levels (d and v arenas)
  k_fdft<<<dim3(37, 4, 2), dim3(256), 0, stream>>>(DD, VD, XDre, XDim, XVre, XVim);

  // 7. per-frequency channel mix, all 44 rows per block, K-split x4
  k_mix2<<<dim3(16, 4, 4), dim3(512), 0, stream>>>(
      XDre, XDim, XVre, XVim, W4, W2, Ar, Ai, Br, Bi, Cr, Ci,
      Part, use_wt ? 1 : 0);

  // 7b. reduce K-chunk partials
  k_reduce<<<dim3((XPLANE + 255) / 256), dim3(256), 0, stream>>>(
      Part, UdFre, UdFim, UsFre, UsFim);

  // 8. inverse DFTs into time-domain Ud/Us arenas (alias DD/VD)
  k_idft<<<dim3(513, 4), dim3(256), 0, stream>>>(UdFre, UdFim, UsFre, UsFim, UdT, UsT);

  // 9. reconstruction j = 11..1 (ping-pong RA/RB)
  float* cur = RA;
  float* nxt = RB;
  for (int j = 11; j >= 1; --j) {
    int Lc = 4096 >> j;
    int abase = 4 * (4096 - (4096 >> (j - 1)));
    k_recon<<<dim3(Lc), dim3(256), 0, stream>>>(cur, UdT, UsT, rc_e, rc_o, nxt, Lc, abase);
    float* t = cur; cur = nxt; nxt = t;
  }

  // 10. Lk1 GEMM on first 3072 rows of final buffer (pitch 4096)
  k_gemm512<<<dim3(192, 8), dim3(256), 0, stream>>>(cur, Lk1_w, Lk1_b, out, 1);
}

// Round 3
// 655.845 us; speedup vs baseline: 1.3795x; 1.1897x over previous
//
#include <hip/hip_runtime.h>

#define CKD 512
#define NROWS 44
#define XPLANE 360448  // 16*44*512

static __device__ __forceinline__ int imin(int a, int b) { return a < b ? a : b; }

typedef short bf16x8 __attribute__((ext_vector_type(8)));
typedef float f32x4 __attribute__((ext_vector_type(4)));

// RNE float->bf16 pack of two floats into one u32
static __device__ __forceinline__ unsigned int pk2(float a, float b) {
  unsigned int ua = __float_as_uint(a), ub = __float_as_uint(b);
  ua = (ua + 0x7fffu + ((ua >> 16) & 1u)) >> 16;
  ub = (ub + 0x7fffu + ((ub >> 16) & 1u)) >> 16;
  return ua | (ub << 16);
}

// ---------------------------------------------------------------------------
// Convert x (4,3072,512) fp32 -> Xb (4,4096,512) bf16 with wraparound pad
// ---------------------------------------------------------------------------
__global__ __launch_bounds__(256) void k_cvt_x(
    const float* __restrict__ src, unsigned short* __restrict__ dst)
{
  int g = blockIdx.x * 256 + threadIdx.x;      // 16384*64
  int row = g >> 6, c8 = (g & 63) << 3;
  int b = row >> 12, t = row & 4095;
  if (t >= 3072) t -= 3072;
  const float* s = src + ((size_t)(b * 3072 + t) << 9) + c8;
  float4 v0 = *(const float4*)s;
  float4 v1 = *(const float4*)(s + 4);
  uint4 o = make_uint4(pk2(v0.x, v0.y), pk2(v0.z, v0.w),
                       pk2(v1.x, v1.y), pk2(v1.z, v1.w));
  *(uint4*)(dst + ((size_t)row << 9) + c8) = o;
}

// ---------------------------------------------------------------------------
// Convert contiguous fp32 -> bf16 (weights), n/8 threads
// ---------------------------------------------------------------------------
__global__ __launch_bounds__(256) void k_cvt_gen(
    const float* __restrict__ src, unsigned short* __restrict__ dst)
{
  int g = blockIdx.x * 256 + threadIdx.x;
  const float* s = src + ((size_t)g << 3);
  float4 v0 = *(const float4*)s;
  float4 v1 = *(const float4*)(s + 4);
  uint4 o = make_uint4(pk2(v0.x, v0.y), pk2(v0.z, v0.w),
                       pk2(v1.x, v1.y), pk2(v1.z, v1.w));
  *(uint4*)(dst + ((size_t)g << 3)) = o;
}

// ---------------------------------------------------------------------------
// Convert recon result (4,4096,512) fp32, rows t<3072 -> Cb (12288,512) bf16
// ---------------------------------------------------------------------------
__global__ __launch_bounds__(256) void k_cvt_c(
    const float* __restrict__ src, unsigned short* __restrict__ dst)
{
  int g = blockIdx.x * 256 + threadIdx.x;      // 12288*64
  int row = g >> 6, c8 = (g & 63) << 3;
  int b = row / 3072, t = row - b * 3072;
  const float* s = src + ((size_t)((b << 12) + t) << 9) + c8;
  float4 v0 = *(const float4*)s;
  float4 v1 = *(const float4*)(s + 4);
  uint4 o = make_uint4(pk2(v0.x, v0.y), pk2(v0.z, v0.w),
                       pk2(v1.x, v1.y), pk2(v1.z, v1.w));
  *(uint4*)(dst + ((size_t)row << 9) + c8) = o;
}

// ---------------------------------------------------------------------------
// bf16 MFMA GEMM: Out[m][n] = sum_k A[m][k]*W[n][k] + bias[n], K=N=512
// 128x128 tile, 256 threads (4 waves, each 64x64), BK=32, 16x16x32 mfma
// ---------------------------------------------------------------------------
__global__ __launch_bounds__(256) void k_gemm_bf16(
    const unsigned short* __restrict__ A, const unsigned short* __restrict__ W,
    const float* __restrict__ bias, float* __restrict__ Out)
{
  __shared__ unsigned short As[128 * 40];
  __shared__ unsigned short Bs[128 * 40];
  const int tid = threadIdx.x;
  const int row = tid >> 1, half = tid & 1;
  const int bm0 = blockIdx.x << 7, bn0 = blockIdx.y << 7;
  const int wv = tid >> 6, l = tid & 63;
  const int wm0 = (wv & 1) << 6, wn0 = (wv >> 1) << 6;
  const int fr = l & 15, fq = l >> 4;

  const unsigned short* Ap = A + (size_t)(bm0 + row) * CKD + half * 16;
  const unsigned short* Wp = W + (size_t)(bn0 + row) * CKD + half * 16;

  f32x4 acc[4][4];
#pragma unroll
  for (int mt = 0; mt < 4; ++mt)
#pragma unroll
    for (int nt = 0; nt < 4; ++nt) {
      acc[mt][nt][0] = 0.f; acc[mt][nt][1] = 0.f;
      acc[mt][nt][2] = 0.f; acc[mt][nt][3] = 0.f;
    }

  for (int k0 = 0; k0 < CKD; k0 += 32) {
    uint4 av0 = *(const uint4*)(Ap + k0);
    uint4 av1 = *(const uint4*)(Ap + k0 + 8);
    uint4 bv0 = *(const uint4*)(Wp + k0);
    uint4 bv1 = *(const uint4*)(Wp + k0 + 8);
    __syncthreads();
    *(uint4*)&As[row * 40 + half * 16]     = av0;
    *(uint4*)&As[row * 40 + half * 16 + 8] = av1;
    *(uint4*)&Bs[row * 40 + half * 16]     = bv0;
    *(uint4*)&Bs[row * 40 + half * 16 + 8] = bv1;
    __syncthreads();
    bf16x8 af[4], bfr[4];
#pragma unroll
    for (int mt = 0; mt < 4; ++mt)
      af[mt] = *(const bf16x8*)&As[(wm0 + mt * 16 + fr) * 40 + fq * 8];
#pragma unroll
    for (int nt = 0; nt < 4; ++nt)
      bfr[nt] = *(const bf16x8*)&Bs[(wn0 + nt * 16 + fr) * 40 + fq * 8];
#pragma unroll
    for (int mt = 0; mt < 4; ++mt)
#pragma unroll
      for (int nt = 0; nt < 4; ++nt)
        acc[mt][nt] = __builtin_amdgcn_mfma_f32_16x16x32_bf16(
            af[mt], bfr[nt], acc[mt][nt], 0, 0, 0);
  }

#pragma unroll
  for (int nt = 0; nt < 4; ++nt) {
    int col = bn0 + wn0 + nt * 16 + fr;
    float bv = bias[col];
#pragma unroll
    for (int mt = 0; mt < 4; ++mt) {
      int r0 = bm0 + wm0 + mt * 16 + fq * 4;
#pragma unroll
      for (int rg = 0; rg < 4; ++rg)
        Out[(size_t)(r0 + rg) * CKD + col] = acc[mt][nt][rg] + bv;
    }
  }
}

// ---------------------------------------------------------------------------
// Decomposition step: xa = [v[2s], v[2s+1]] (16), d = xa@ec_d, v' = xa@ec_s
// ---------------------------------------------------------------------------
__global__ __launch_bounds__(256) void k_decomp(
    const float* __restrict__ Vin, const float* __restrict__ ec_s,
    const float* __restrict__ ec_d, float* __restrict__ Dout,
    float* __restrict__ Vout, int Lout, int pin)
{
  __shared__ float Es[128], Ed[128];
  if (threadIdx.x < 128) Es[threadIdx.x] = ec_s[threadIdx.x];
  else Ed[threadIdx.x - 128] = ec_d[threadIdx.x - 128];
  __syncthreads();
  int g = blockIdx.x * 256 + threadIdx.x;
  if (g >= 4 * Lout * 64) return;
  int c = g & 63;
  int s = (g >> 6) % Lout;
  int b = g / (Lout << 6);
  const float* r0 = Vin + ((size_t)b * pin + 2 * s) * CKD + (c << 3);
  float a[16];
  float4 v0 = *(const float4*)r0;
  float4 v1 = *(const float4*)(r0 + 4);
  float4 v2 = *(const float4*)(r0 + CKD);
  float4 v3 = *(const float4*)(r0 + CKD + 4);
  a[0]=v0.x; a[1]=v0.y; a[2]=v0.z; a[3]=v0.w; a[4]=v1.x; a[5]=v1.y; a[6]=v1.z; a[7]=v1.w;
  a[8]=v2.x; a[9]=v2.y; a[10]=v2.z; a[11]=v2.w; a[12]=v3.x; a[13]=v3.y; a[14]=v3.z; a[15]=v3.w;
  float dv[8] = {}, vv[8] = {};
#pragma unroll
  for (int m = 0; m < 16; ++m)
#pragma unroll
    for (int k = 0; k < 8; ++k) {
      dv[k] += a[m] * Ed[m * 8 + k];
      vv[k] += a[m] * Es[m * 8 + k];
    }
  size_t orow = ((size_t)b * Lout + s) * CKD + (c << 3);
  *(float4*)(Dout + orow)     = make_float4(dv[0], dv[1], dv[2], dv[3]);
  *(float4*)(Dout + orow + 4) = make_float4(dv[4], dv[5], dv[6], dv[7]);
  *(float4*)(Vout + orow)     = make_float4(vv[0], vv[1], vv[2], vv[3]);
  *(float4*)(Vout + orow + 4) = make_float4(vv[4], vv[5], vv[6], vv[7]);
}

// ---------------------------------------------------------------------------
// T0
// ---------------------------------------------------------------------------
__global__ __launch_bounds__(256) void k_t0(
    const float* __restrict__ Vin, const float* __restrict__ T0w,
    const float* __restrict__ T0b, float* __restrict__ Out)
{
  int g = blockIdx.x * 256 + threadIdx.x;
  if (g >= 4 * 2 * 64) return;
  int c = g & 63;
  int t = (g >> 6) & 1;
  int b = g >> 7;
  const float* src = Vin + ((size_t)(b * 2 + t)) * CKD + (c << 3);
  float a[8];
  float4 v0 = *(const float4*)src;
  float4 v1 = *(const float4*)(src + 4);
  a[0]=v0.x; a[1]=v0.y; a[2]=v0.z; a[3]=v0.w; a[4]=v1.x; a[5]=v1.y; a[6]=v1.z; a[7]=v1.w;
  float o[8];
#pragma unroll
  for (int ko = 0; ko < 8; ++ko) {
    float sum = T0b[ko];
#pragma unroll
    for (int k = 0; k < 8; ++k) sum += a[k] * T0w[ko * 8 + k];
    o[ko] = sum;
  }
  float* dst = Out + ((size_t)(b * 2 + t)) * CKD + (c << 3);
  *(float4*)dst       = make_float4(o[0], o[1], o[2], o[3]);
  *(float4*)(dst + 4) = make_float4(o[4], o[5], o[6], o[7]);
}

// ---------------------------------------------------------------------------
// Forward truncated DFT (atomic accumulate over t-chunks)
// ---------------------------------------------------------------------------
__global__ __launch_bounds__(256) void k_fdft(
    const float* __restrict__ DD, const float* __restrict__ VD,
    float* __restrict__ XDre, float* __restrict__ XDim,
    float* __restrict__ XVre, float* __restrict__ XVim)
{
  __shared__ float2 tw[2048];  // [f][128]
  int bx = blockIdx.x, j = 1;
  for (;;) {
    int c = (4096 >> j) >> 7; if (c < 1) c = 1;
    if (bx < c) break;
    bx -= c; ++j;
  }
  const int L = 4096 >> j;
  const int t0 = bx << 7;
  const int tcnt = imin(128, L - t0);
  const int b = blockIdx.y;
  const int z = blockIdx.z;
  const int r = (j - 1) * 4 + b;
  const float* src = (z ? VD : DD) +
      ((size_t)(4 * (4096 - (4096 >> (j - 1))) + b * L)) * CKD;
  float* dre = z ? XVre : XDre;
  float* dim_ = z ? XVim : XDim;

  for (int idx = threadIdx.x; idx < 2048; idx += 256) {
    int ff = idx >> 7, tl = idx & 127;
    int t = t0 + tl;
    int m = (2 * ff * t) & (2 * L - 1);
    float xang = (float)m / (float)L;
    tw[idx] = make_float2(cospif(xang), sinpif(xang));
  }
  __syncthreads();

  float ar[16][2] = {};
  float ai[16][2] = {};
  const float* sp = src + (size_t)t0 * CKD + (threadIdx.x << 1);
  for (int tl = 0; tl < tcnt; ++tl) {
    float2 xv = *(const float2*)sp;
    sp += CKD;
#pragma unroll
    for (int ff = 0; ff < 16; ++ff) {
      float2 cs = tw[(ff << 7) + tl];
      ar[ff][0] += xv.x * cs.x; ar[ff][1] += xv.y * cs.x;
      ai[ff][0] -= xv.x * cs.y; ai[ff][1] -= xv.y * cs.y;
    }
  }
  const int i0 = threadIdx.x << 1;
#pragma unroll
  for (int ff = 0; ff < 16; ++ff) {
    size_t bidx = ((size_t)ff * NROWS + r) * CKD + i0;
    atomicAdd(&dre[bidx], ar[ff][0]);
    atomicAdd(&dre[bidx + 1], ar[ff][1]);
    atomicAdd(&dim_[bidx], ai[ff][0]);
    atomicAdd(&dim_[bidx + 1], ai[ff][1]);
  }
}

// ---------------------------------------------------------------------------
// Fused weight repack: (i,o,f) x6 -> W4[f][i][o] = (Ar,Ai,Br,Bi) float4
//                                   W2[f][i][o] = (Cr,Ci) float2
// ---------------------------------------------------------------------------
__global__ __launch_bounds__(256) void k_transw6(
    const float* __restrict__ sAr, const float* __restrict__ sAi,
    const float* __restrict__ sBr, const float* __restrict__ sBi,
    const float* __restrict__ sCr, const float* __restrict__ sCi,
    float* __restrict__ W4, float* __restrict__ W2)
{
  int g = blockIdx.x * 256 + threadIdx.x;  // i*512 + o
  float ar[16], ai[16], br[16], bi[16], cr[16], ci[16];
  const size_t sb = (size_t)g * 16;
#pragma unroll
  for (int q = 0; q < 4; ++q) {
    float4 t;
    t = *(const float4*)(sAr + sb + q * 4); ar[q*4]=t.x; ar[q*4+1]=t.y; ar[q*4+2]=t.z; ar[q*4+3]=t.w;
    t = *(const float4*)(sAi + sb + q * 4); ai[q*4]=t.x; ai[q*4+1]=t.y; ai[q*4+2]=t.z; ai[q*4+3]=t.w;
    t = *(const float4*)(sBr + sb + q * 4); br[q*4]=t.x; br[q*4+1]=t.y; br[q*4+2]=t.z; br[q*4+3]=t.w;
    t = *(const float4*)(sBi + sb + q * 4); bi[q*4]=t.x; bi[q*4+1]=t.y; bi[q*4+2]=t.z; bi[q*4+3]=t.w;
    t = *(const float4*)(sCr + sb + q * 4); cr[q*4]=t.x; cr[q*4+1]=t.y; cr[q*4+2]=t.z; cr[q*4+3]=t.w;
    t = *(const float4*)(sCi + sb + q * 4); ci[q*4]=t.x; ci[q*4+1]=t.y; ci[q*4+2]=t.z; ci[q*4+3]=t.w;
  }
#pragma unroll
  for (int f = 0; f < 16; ++f) {
    size_t e = ((size_t)f << 18) + g;  // f*262144 + i*512 + o
    *(float4*)(W4 + (e << 2)) = make_float4(ar[f], ai[f], br[f], bi[f]);
    *(float2*)(W2 + (e << 1)) = make_float2(cr[f], ci[f]);
  }
}

// ---------------------------------------------------------------------------
// Channel mix v3: per (f, o-tile of 128, K-chunk of 64) block, ALL 44 rows.
// 512 threads = 64 o-lanes x 8 row-groups. Partials into PartA (kc<5) / PartB.
// ---------------------------------------------------------------------------
__global__ __launch_bounds__(512) void k_mix2(
    const float* __restrict__ XDre, const float* __restrict__ XDim,
    const float* __restrict__ XVre, const float* __restrict__ XVim,
    const float* __restrict__ W4, const float* __restrict__ W2,
    const float* __restrict__ war, const float* __restrict__ wai,
    const float* __restrict__ wbr, const float* __restrict__ wbi,
    const float* __restrict__ wcr, const float* __restrict__ wci,
    float* __restrict__ PartA, float* __restrict__ PartB, int wt_mode)
{
  const int f = blockIdx.x;
  const int ot = blockIdx.y;   // 0..3
  const int kc = blockIdx.z;   // 0..7
  const int lane = threadIdx.x & 63;
  const int rg = threadIdx.x >> 6;           // 0..7
  const int rbase = (rg < 4) ? rg * 6 : 24 + (rg - 4) * 5;
  const int rcnt = (rg < 4) ? 6 : 5;
  const int o0 = (ot << 7) + lane;           // covers o0 and o0+64
  const int i0 = kc << 6;

  __shared__ float4 sx[NROWS * 64];          // 45 KiB

  float udr[6][2] = {}, udi[6][2] = {}, usr[6][2] = {}, usi[6][2] = {};

  for (int idx = threadIdx.x; idx < NROWS * 64; idx += 512) {
    int r = idx >> 6, il = idx & 63;
    size_t xb = ((size_t)f * NROWS + r) * CKD + i0 + il;
    sx[idx] = make_float4(XDre[xb], XDim[xb], XVre[xb], XVim[xb]);
  }
  __syncthreads();
#pragma unroll 2
  for (int ii = 0; ii < 64; ++ii) {
    const int i = i0 + ii;
    float4 wa0, wa1; float2 wc0, wc1;
    if (wt_mode) {
      size_t e = (((size_t)f << 9) + i) << 9;  // (f*512 + i)*512
      wa0 = *(const float4*)(W4 + ((e + o0) << 2));
      wa1 = *(const float4*)(W4 + ((e + o0 + 64) << 2));
      wc0 = *(const float2*)(W2 + ((e + o0) << 1));
      wc1 = *(const float2*)(W2 + ((e + o0 + 64) << 1));
    } else {
      size_t wo = ((((size_t)i << 9) + o0) << 4) + f;
      wa0 = make_float4(war[wo], wai[wo], wbr[wo], wbi[wo]);
      wc0 = make_float2(wcr[wo], wci[wo]);
      size_t w1 = wo + (64u << 4);
      wa1 = make_float4(war[w1], wai[w1], wbr[w1], wbi[w1]);
      wc1 = make_float2(wcr[w1], wci[w1]);
    }
#pragma unroll
    for (int rr = 0; rr < 6; ++rr) {
      if (rr < rcnt) {
        float4 xv = sx[((rbase + rr) << 6) + ii];
        udr[rr][0] += xv.x * wa0.x - xv.y * wa0.y + xv.z * wa0.z - xv.w * wa0.w;
        udi[rr][0] += xv.x * wa0.y + xv.y * wa0.x + xv.z * wa0.w + xv.w * wa0.z;
        usr[rr][0] += xv.x * wc0.x - xv.y * wc0.y;
        usi[rr][0] += xv.x * wc0.y + xv.y * wc0.x;
        udr[rr][1] += xv.x * wa1.x - xv.y * wa1.y + xv.z * wa1.z - xv.w * wa1.w;
        udi[rr][1] += xv.x * wa1.y + xv.y * wa1.x + xv.z * wa1.w + xv.w * wa1.z;
        usr[rr][1] += xv.x * wc1.x - xv.y * wc1.y;
        usi[rr][1] += xv.x * wc1.y + xv.y * wc1.x;
      }
    }
  }

  float* P = (kc < 5) ? PartA + (size_t)kc * 4 * XPLANE
                      : PartB + (size_t)(kc - 5) * 4 * XPLANE;
#pragma unroll
  for (int rr = 0; rr < 6; ++rr) {
    if (rr < rcnt) {
      size_t rb_ = ((size_t)f * NROWS + rbase + rr) * CKD;
      P[0 * XPLANE + rb_ + o0]      = udr[rr][0];
      P[1 * XPLANE + rb_ + o0]      = udi[rr][0];
      P[2 * XPLANE + rb_ + o0]      = usr[rr][0];
      P[3 * XPLANE + rb_ + o0]      = usi[rr][0];
      P[0 * XPLANE + rb_ + o0 + 64] = udr[rr][1];
      P[1 * XPLANE + rb_ + o0 + 64] = udi[rr][1];
      P[2 * XPLANE + rb_ + o0 + 64] = usr[rr][1];
      P[3 * XPLANE + rb_ + o0 + 64] = usi[rr][1];
    }
  }
}

// ---------------------------------------------------------------------------
// Reduce 8 K-chunk partials (5 in A, 3 in B) -> final spectral UdF/UsF
// ---------------------------------------------------------------------------
__global__ __launch_bounds__(256) void k_reduce(
    const float* __restrict__ PartA, const float* __restrict__ PartB,
    float* __restrict__ UdFre, float* __restrict__ UdFim,
    float* __restrict__ UsFre, float* __restrict__ UsFim)
{
  int idx = blockIdx.x * 256 + threadIdx.x;
  if (idx >= XPLANE) return;
  float s0 = 0.f, s1 = 0.f, s2 = 0.f, s3 = 0.f;
#pragma unroll
  for (int kc = 0; kc < 5; ++kc) {
    const float* p = PartA + (size_t)kc * 4 * XPLANE;
    s0 += p[0 * XPLANE + idx];
    s1 += p[1 * XPLANE + idx];
    s2 += p[2 * XPLANE + idx];
    s3 += p[3 * XPLANE + idx];
  }
#pragma unroll
  for (int kc = 0; kc < 3; ++kc) {
    const float* p = PartB + (size_t)kc * 4 * XPLANE;
    s0 += p[0 * XPLANE + idx];
    s1 += p[1 * XPLANE + idx];
    s2 += p[2 * XPLANE + idx];
    s3 += p[3 * XPLANE + idx];
  }
  UdFre[idx] = s0; UdFim[idx] = s1; UsFre[idx] = s2; UsFim[idx] = s3;
}

// ---------------------------------------------------------------------------
// Inverse truncated DFT
// ---------------------------------------------------------------------------
__global__ __launch_bounds__(256) void k_idft(
    const float* __restrict__ UdFre, const float* __restrict__ UdFim,
    const float* __restrict__ UsFre, const float* __restrict__ UsFim,
    float* __restrict__ UdT, float* __restrict__ UsT)
{
  __shared__ float2 tw[128];  // [f][8]
  int bx = blockIdx.x, j = 1;
  for (;;) {
    int c = (4096 >> j) >> 3; if (c < 1) c = 1;
    if (bx < c) break;
    bx -= c; ++j;
  }
  const int L = 4096 >> j;
  const int l = imin(16, (L >> 1) + 1);
  const int t0 = bx << 3;
  const int b = blockIdx.y;
  const int r = (j - 1) * 4 + b;
  if (threadIdx.x < 128) {
    int ff = threadIdx.x >> 3, tl = threadIdx.x & 7;
    int t = t0 + tl;
    int m = (2 * ff * t) & (2 * L - 1);
    float xang = (float)m / (float)L;
    float wgt = (ff == 0 || 2 * ff == L) ? 1.0f : 2.0f;
    float sc = wgt / (float)L;
    tw[threadIdx.x] = make_float2(cospif(xang) * sc, sinpif(xang) * sc);
  }
  __syncthreads();
  const int o = threadIdx.x << 1;
  float2 ud[8], us[8];
#pragma unroll
  for (int tl = 0; tl < 8; ++tl) { ud[tl] = make_float2(0.f, 0.f); us[tl] = make_float2(0.f, 0.f); }
  for (int ff = 0; ff < l; ++ff) {
    size_t bidx = ((size_t)ff * NROWS + r) * CKD + o;
    float2 er = *(const float2*)(UdFre + bidx);
    float2 ei = *(const float2*)(UdFim + bidx);
    float2 sr = *(const float2*)(UsFre + bidx);
    float2 si = *(const float2*)(UsFim + bidx);
#pragma unroll
    for (int tl = 0; tl < 8; ++tl) {
      float2 cs = tw[(ff << 3) + tl];
      ud[tl].x += er.x * cs.x - ei.x * cs.y;
      ud[tl].y += er.y * cs.x - ei.y * cs.y;
      us[tl].x += sr.x * cs.x - si.x * cs.y;
      us[tl].y += sr.y * cs.x - si.y * cs.y;
    }
  }
  int tmax = imin(8, L - t0);
  size_t obase = ((size_t)(4 * (4096 - (4096 >> (j - 1))) + b * L + t0)) * CKD + o;
  for (int tl = 0; tl < tmax; ++tl) {
    *(float2*)(UdT + obase + (size_t)tl * CKD) = ud[tl];
    *(float2*)(UsT + obase + (size_t)tl * CKD) = us[tl];
  }
}

// ---------------------------------------------------------------------------
// Reconstruction
// ---------------------------------------------------------------------------
__global__ __launch_bounds__(256) void k_recon(
    const float* __restrict__ Vcur, const float* __restrict__ UdT,
    const float* __restrict__ UsT, const float* __restrict__ rc_e,
    const float* __restrict__ rc_o, float* __restrict__ Vnext,
    int Lc, int abase)
{
  __shared__ float Re[128], Ro[128];
  if (threadIdx.x < 128) Re[threadIdx.x] = rc_e[threadIdx.x];
  else Ro[threadIdx.x - 128] = rc_o[threadIdx.x - 128];
  __syncthreads();
  int g = blockIdx.x * 256 + threadIdx.x;
  if (g >= 4 * Lc * 64) return;
  int c = g & 63;
  int s = (g >> 6) % Lc;
  int b = g / (Lc << 6);
  size_t vrow = ((size_t)b * Lc + s) * CKD + (c << 3);
  size_t arow = ((size_t)abase + (size_t)b * Lc + s) * CKD + (c << 3);
  float a[16];
  {
    float4 t0_ = *(const float4*)(Vcur + vrow);
    float4 t1_ = *(const float4*)(Vcur + vrow + 4);
    float4 u0 = *(const float4*)(UsT + arow);
    float4 u1 = *(const float4*)(UsT + arow + 4);
    a[0]=t0_.x+u0.x; a[1]=t0_.y+u0.y; a[2]=t0_.z+u0.z; a[3]=t0_.w+u0.w;
    a[4]=t1_.x+u1.x; a[5]=t1_.y+u1.y; a[6]=t1_.z+u1.z; a[7]=t1_.w+u1.w;
    float4 d0 = *(const float4*)(UdT + arow);
    float4 d1 = *(const float4*)(UdT + arow + 4);
    a[8]=d0.x; a[9]=d0.y; a[10]=d0.z; a[11]=d0.w;
    a[12]=d1.x; a[13]=d1.y; a[14]=d1.z; a[15]=d1.w;
  }
  float xe[8] = {}, xo[8] = {};
#pragma unroll
  for (int m = 0; m < 16; ++m)
#pragma unroll
    for (int k = 0; k < 8; ++k) {
      xe[k] += a[m] * Re[m * 8 + k];
      xo[k] += a[m] * Ro[m * 8 + k];
    }
  size_t orow = ((size_t)b * (Lc << 1) + (s << 1)) * CKD + (c << 3);
  *(float4*)(Vnext + orow)           = make_float4(xe[0], xe[1], xe[2], xe[3]);
  *(float4*)(Vnext + orow + 4)       = make_float4(xe[4], xe[5], xe[6], xe[7]);
  *(float4*)(Vnext + orow + CKD)     = make_float4(xo[0], xo[1], xo[2], xo[3]);
  *(float4*)(Vnext + orow + CKD + 4) = make_float4(xo[4], xo[5], xo[6], xo[7]);
}

// ---------------------------------------------------------------------------
extern "C" void kernel_launch(void* const* d_in, const int* in_sizes, int n_in,
                              void* d_out, int out_size, void* d_ws, size_t ws_size,
                              hipStream_t stream)
{
  const float* x     = (const float*)d_in[0];
  const float* Lk0_w = (const float*)d_in[1];
  const float* Lk0_b = (const float*)d_in[2];
  const float* Lk1_w = (const float*)d_in[3];
  const float* Lk1_b = (const float*)d_in[4];
  const float* T0_w  = (const float*)d_in[5];
  const float* T0_b  = (const float*)d_in[6];
  const float* Ar = (const float*)d_in[7];
  const float* Ai = (const float*)d_in[8];
  const float* Br = (const float*)d_in[9];
  const float* Bi = (const float*)d_in[10];
  const float* Cr = (const float*)d_in[11];
  const float* Ci = (const float*)d_in[12];
  const float* ec_s = (const float*)d_in[13];
  const float* ec_d = (const float*)d_in[14];
  const float* rc_e = (const float*)d_in[15];
  const float* rc_o = (const float*)d_in[16];
  float* out = (float*)d_out;

  // workspace layout (floats)
  float* w = (float*)d_ws;
  float* V0 = w;   w += (size_t)4 * 4096 * 512;  // 8,388,608  (RA; tail = PartB)
  float* VD = w;   w += (size_t)4 * 4094 * 512;  // 8,380,416  (aliased as UsT)
  float* DD = w;   w += (size_t)4 * 4094 * 512;  // 8,380,416  (aliased as UdT; late: Cb)
  float* RB = w;   w += (size_t)4 * 4096 * 512;  // 8,388,608  (early: Xb bf16; mix PartA)
  float* XDre = w; w += XPLANE;
  float* XDim = w; w += XPLANE;
  float* XVre = w; w += XPLANE;
  float* XVim = w; w += XPLANE;
  float* UdFre = w; w += XPLANE;   // early: Wb0 bf16; late: Wb1 bf16
  float* UdFim = w; w += XPLANE;
  float* UsFre = w; w += XPLANE;
  float* UsFim = w; w += XPLANE;
  float* WT = w;  // W4 (16.78M) + W2 (8.39M) if it fits
  float* RA = V0;
  float* UdT = DD;
  float* UsT = VD;
  float* PartA = RB;               // 5 chunks * 1.44M = 7.2M <= 8.39M
  float* PartB = V0 + 65536;       // 3 chunks * 1.44M = 4.3M <= 8.3M

  unsigned short* Xb  = (unsigned short*)RB;     // 16384*512 bf16 = 4.19M floats
  unsigned short* Cb  = (unsigned short*)DD;     // 12288*512 bf16 = 3.15M floats
  unsigned short* Wb0 = (unsigned short*)UdFre;  // 512*512 bf16 = 0.131M floats
  unsigned short* Wb1 = (unsigned short*)UdFre;

  const size_t BASE_FLOATS = 36421632ull;
  const size_t WT_FLOATS   = 25165824ull;
  if (ws_size < BASE_FLOATS * 4) return;  // cannot run
  const bool use_wt = ws_size >= (BASE_FLOATS + WT_FLOATS) * 4;
  float* W4 = WT;
  float* W2 = WT + 16777216ull;

  // 1. convert inputs to bf16 and run Lk0 GEMM (MFMA)
  k_cvt_x<<<dim3(4096), dim3(256), 0, stream>>>(x, Xb);
  k_cvt_gen<<<dim3(128), dim3(256), 0, stream>>>(Lk0_w, Wb0);
  k_gemm_bf16<<<dim3(128, 4), dim3(256), 0, stream>>>(Xb, Wb0, Lk0_b, V0);

  // 2. decomposition levels j = 1..11
  for (int j = 1; j <= 11; ++j) {
    int Lout = 4096 >> j;
    int pin = 4096 >> (j - 1);
    const float* vin = (j == 1)
        ? V0
        : VD + (size_t)4 * (4096 - (4096 >> (j - 2))) * 512;
    size_t base = (size_t)4 * (4096 - (4096 >> (j - 1))) * 512;
    k_decomp<<<dim3(Lout), dim3(256), 0, stream>>>(vin, ec_s, ec_d,
                                                   DD + base, VD + base, Lout, pin);
  }

  // 3. T0 on v_11
  k_t0<<<dim3(2), dim3(256), 0, stream>>>(VD + (size_t)4 * 4092 * 512, T0_w, T0_b, RA);

  // 4. zero X accumulators
  hipMemsetAsync(XDre, 0, (size_t)4 * XPLANE * 4, stream);

  // 5. weight repack (i,o,f) -> interleaved [f][i][o] float4/float2
  if (use_wt)
    k_transw6<<<dim3(1024), dim3(256), 0, stream>>>(Ar, Ai, Br, Bi, Cr, Ci, W4, W2);

  // 6. forward DFTs of all levels
  k_fdft<<<dim3(37, 4, 2), dim3(256), 0, stream>>>(DD, VD, XDre, XDim, XVre, XVim);

  // 7. per-frequency channel mix, all 44 rows per block, K-split x8
  k_mix2<<<dim3(16, 4, 8), dim3(512), 0, stream>>>(
      XDre, XDim, XVre, XVim, W4, W2, Ar, Ai, Br, Bi, Cr, Ci,
      PartA, PartB, use_wt ? 1 : 0);

  // 7b. reduce K-chunk partials
  k_reduce<<<dim3((XPLANE + 255) / 256), dim3(256), 0, stream>>>(
      PartA, PartB, UdFre, UdFim, UsFre, UsFim);

  // 8. inverse DFTs into time-domain Ud/Us arenas (alias DD/VD)
  k_idft<<<dim3(513, 4), dim3(256), 0, stream>>>(UdFre, UdFim, UsFre, UsFim, UdT, UsT);

  // 9. reconstruction j = 11..1 (ping-pong RA/RB; 11 steps -> final in RB)
  float* cur = RA;
  float* nxt = RB;
  for (int j = 11; j >= 1; --j) {
    int Lc = 4096 >> j;
    int abase = 4 * (4096 - (4096 >> (j - 1)));
    k_recon<<<dim3(Lc), dim3(256), 0, stream>>>(cur, UdT, UsT, rc_e, rc_o, nxt, Lc, abase);
    float* t = cur; cur = nxt; nxt = t;
  }

  // 10. convert recon result + Lk1 weights to bf16; Lk1 GEMM (MFMA)
  k_cvt_c<<<dim3(3072), dim3(256), 0, stream>>>(cur, Cb);
  k_cvt_gen<<<dim3(128), dim3(256), 0, stream>>>(Lk1_w, Wb1);
  k_gemm_bf16<<<dim3(96, 4), dim3(256), 0, stream>>>(Cb, Wb1, Lk1_b, out);
}

// Round 4
// 522.776 us; speedup vs baseline: 1.7307x; 1.2545x over previous
//
#include <hip/hip_runtime.h>

#define CKD 512
#define NROWS 44
#define XPLANE 360448  // 16*44*512

static __device__ __forceinline__ int imin(int a, int b) { return a < b ? a : b; }

typedef short bf16x8 __attribute__((ext_vector_type(8)));
typedef float f32x4 __attribute__((ext_vector_type(4)));
typedef unsigned int uint32;
typedef unsigned short ushort16;

// RNE float->bf16 pack of two floats into one u32 (lo = a, hi = b)
static __device__ __forceinline__ unsigned int pk2(float a, float b) {
  unsigned int ua = __float_as_uint(a), ub = __float_as_uint(b);
  ua = (ua + 0x7fffu + ((ua >> 16) & 1u)) >> 16;
  ub = (ub + 0x7fffu + ((ub >> 16) & 1u)) >> 16;
  return ua | (ub << 16);
}

static __device__ __forceinline__ uint32 ror16(uint32 q) { return (q >> 16) | (q << 16); }

// frag from 4 packed words, negating the HIGH bf16 of each (lo, -hi)
static __device__ __forceinline__ bf16x8 mk_neghi(uint32 q0, uint32 q1, uint32 q2, uint32 q3) {
  union { uint32 u[4]; bf16x8 h; } t;
  t.u[0] = q0 ^ 0x80000000u; t.u[1] = q1 ^ 0x80000000u;
  t.u[2] = q2 ^ 0x80000000u; t.u[3] = q3 ^ 0x80000000u;
  return t.h;
}
// frag from 4 packed words, swapping halves (hi, lo)
static __device__ __forceinline__ bf16x8 mk_swap(uint32 q0, uint32 q1, uint32 q2, uint32 q3) {
  union { uint32 u[4]; bf16x8 h; } t;
  t.u[0] = ror16(q0); t.u[1] = ror16(q1); t.u[2] = ror16(q2); t.u[3] = ror16(q3);
  return t.h;
}

// ---------------------------------------------------------------------------
// Convert x (4,3072,512) fp32 -> Xb (4,4096,512) bf16 with wraparound pad
// ---------------------------------------------------------------------------
__global__ __launch_bounds__(256) void k_cvt_x(
    const float* __restrict__ src, unsigned short* __restrict__ dst)
{
  int g = blockIdx.x * 256 + threadIdx.x;      // 16384*64
  int row = g >> 6, c8 = (g & 63) << 3;
  int b = row >> 12, t = row & 4095;
  if (t >= 3072) t -= 3072;
  const float* s = src + ((size_t)(b * 3072 + t) << 9) + c8;
  float4 v0 = *(const float4*)s;
  float4 v1 = *(const float4*)(s + 4);
  uint4 o = make_uint4(pk2(v0.x, v0.y), pk2(v0.z, v0.w),
                       pk2(v1.x, v1.y), pk2(v1.z, v1.w));
  *(uint4*)(dst + ((size_t)row << 9) + c8) = o;
}

// ---------------------------------------------------------------------------
// Convert contiguous fp32 -> bf16 (weights), n/8 threads
// ---------------------------------------------------------------------------
__global__ __launch_bounds__(256) void k_cvt_gen(
    const float* __restrict__ src, unsigned short* __restrict__ dst)
{
  int g = blockIdx.x * 256 + threadIdx.x;
  const float* s = src + ((size_t)g << 3);
  float4 v0 = *(const float4*)s;
  float4 v1 = *(const float4*)(s + 4);
  uint4 o = make_uint4(pk2(v0.x, v0.y), pk2(v0.z, v0.w),
                       pk2(v1.x, v1.y), pk2(v1.z, v1.w));
  *(uint4*)(dst + ((size_t)g << 3)) = o;
}

// ---------------------------------------------------------------------------
// Convert recon result (4,4096,512) fp32, rows t<3072 -> Cb (12288,512) bf16
// ---------------------------------------------------------------------------
__global__ __launch_bounds__(256) void k_cvt_c(
    const float* __restrict__ src, unsigned short* __restrict__ dst)
{
  int g = blockIdx.x * 256 + threadIdx.x;      // 12288*64
  int row = g >> 6, c8 = (g & 63) << 3;
  int b = row / 3072, t = row - b * 3072;
  const float* s = src + ((size_t)((b << 12) + t) << 9) + c8;
  float4 v0 = *(const float4*)s;
  float4 v1 = *(const float4*)(s + 4);
  uint4 o = make_uint4(pk2(v0.x, v0.y), pk2(v0.z, v0.w),
                       pk2(v1.x, v1.y), pk2(v1.z, v1.w));
  *(uint4*)(dst + ((size_t)row << 9) + c8) = o;
}

// ---------------------------------------------------------------------------
// bf16 MFMA GEMM: Out[m][n] = sum_k A[m][k]*W[n][k] + bias[n], K=N=512
// ---------------------------------------------------------------------------
__global__ __launch_bounds__(256) void k_gemm_bf16(
    const unsigned short* __restrict__ A, const unsigned short* __restrict__ W,
    const float* __restrict__ bias, float* __restrict__ Out)
{
  __shared__ unsigned short As[128 * 40];
  __shared__ unsigned short Bs[128 * 40];
  const int tid = threadIdx.x;
  const int row = tid >> 1, half = tid & 1;
  const int bm0 = blockIdx.x << 7, bn0 = blockIdx.y << 7;
  const int wv = tid >> 6, l = tid & 63;
  const int wm0 = (wv & 1) << 6, wn0 = (wv >> 1) << 6;
  const int fr = l & 15, fq = l >> 4;

  const unsigned short* Ap = A + (size_t)(bm0 + row) * CKD + half * 16;
  const unsigned short* Wp = W + (size_t)(bn0 + row) * CKD + half * 16;

  f32x4 acc[4][4];
#pragma unroll
  for (int mt = 0; mt < 4; ++mt)
#pragma unroll
    for (int nt = 0; nt < 4; ++nt) {
      acc[mt][nt][0] = 0.f; acc[mt][nt][1] = 0.f;
      acc[mt][nt][2] = 0.f; acc[mt][nt][3] = 0.f;
    }

  for (int k0 = 0; k0 < CKD; k0 += 32) {
    uint4 av0 = *(const uint4*)(Ap + k0);
    uint4 av1 = *(const uint4*)(Ap + k0 + 8);
    uint4 bv0 = *(const uint4*)(Wp + k0);
    uint4 bv1 = *(const uint4*)(Wp + k0 + 8);
    __syncthreads();
    *(uint4*)&As[row * 40 + half * 16]     = av0;
    *(uint4*)&As[row * 40 + half * 16 + 8] = av1;
    *(uint4*)&Bs[row * 40 + half * 16]     = bv0;
    *(uint4*)&Bs[row * 40 + half * 16 + 8] = bv1;
    __syncthreads();
    bf16x8 af[4], bfr[4];
#pragma unroll
    for (int mt = 0; mt < 4; ++mt)
      af[mt] = *(const bf16x8*)&As[(wm0 + mt * 16 + fr) * 40 + fq * 8];
#pragma unroll
    for (int nt = 0; nt < 4; ++nt)
      bfr[nt] = *(const bf16x8*)&Bs[(wn0 + nt * 16 + fr) * 40 + fq * 8];
#pragma unroll
    for (int mt = 0; mt < 4; ++mt)
#pragma unroll
      for (int nt = 0; nt < 4; ++nt)
        acc[mt][nt] = __builtin_amdgcn_mfma_f32_16x16x32_bf16(
            af[mt], bfr[nt], acc[mt][nt], 0, 0, 0);
  }

#pragma unroll
  for (int nt = 0; nt < 4; ++nt) {
    int col = bn0 + wn0 + nt * 16 + fr;
    float bv = bias[col];
#pragma unroll
    for (int mt = 0; mt < 4; ++mt) {
      int r0 = bm0 + wm0 + mt * 16 + fq * 4;
#pragma unroll
      for (int rg = 0; rg < 4; ++rg)
        Out[(size_t)(r0 + rg) * CKD + col] = acc[mt][nt][rg] + bv;
    }
  }
}

// ---------------------------------------------------------------------------
// Decomposition step
// ---------------------------------------------------------------------------
__global__ __launch_bounds__(256) void k_decomp(
    const float* __restrict__ Vin, const float* __restrict__ ec_s,
    const float* __restrict__ ec_d, float* __restrict__ Dout,
    float* __restrict__ Vout, int Lout, int pin)
{
  __shared__ float Es[128], Ed[128];
  if (threadIdx.x < 128) Es[threadIdx.x] = ec_s[threadIdx.x];
  else Ed[threadIdx.x - 128] = ec_d[threadIdx.x - 128];
  __syncthreads();
  int g = blockIdx.x * 256 + threadIdx.x;
  if (g >= 4 * Lout * 64) return;
  int c = g & 63;
  int s = (g >> 6) % Lout;
  int b = g / (Lout << 6);
  const float* r0 = Vin + ((size_t)b * pin + 2 * s) * CKD + (c << 3);
  float a[16];
  float4 v0 = *(const float4*)r0;
  float4 v1 = *(const float4*)(r0 + 4);
  float4 v2 = *(const float4*)(r0 + CKD);
  float4 v3 = *(const float4*)(r0 + CKD + 4);
  a[0]=v0.x; a[1]=v0.y; a[2]=v0.z; a[3]=v0.w; a[4]=v1.x; a[5]=v1.y; a[6]=v1.z; a[7]=v1.w;
  a[8]=v2.x; a[9]=v2.y; a[10]=v2.z; a[11]=v2.w; a[12]=v3.x; a[13]=v3.y; a[14]=v3.z; a[15]=v3.w;
  float dv[8] = {}, vv[8] = {};
#pragma unroll
  for (int m = 0; m < 16; ++m)
#pragma unroll
    for (int k = 0; k < 8; ++k) {
      dv[k] += a[m] * Ed[m * 8 + k];
      vv[k] += a[m] * Es[m * 8 + k];
    }
  size_t orow = ((size_t)b * Lout + s) * CKD + (c << 3);
  *(float4*)(Dout + orow)     = make_float4(dv[0], dv[1], dv[2], dv[3]);
  *(float4*)(Dout + orow + 4) = make_float4(dv[4], dv[5], dv[6], dv[7]);
  *(float4*)(Vout + orow)     = make_float4(vv[0], vv[1], vv[2], vv[3]);
  *(float4*)(Vout + orow + 4) = make_float4(vv[4], vv[5], vv[6], vv[7]);
}

// ---------------------------------------------------------------------------
// T0
// ---------------------------------------------------------------------------
__global__ __launch_bounds__(256) void k_t0(
    const float* __restrict__ Vin, const float* __restrict__ T0w,
    const float* __restrict__ T0b, float* __restrict__ Out)
{
  int g = blockIdx.x * 256 + threadIdx.x;
  if (g >= 4 * 2 * 64) return;
  int c = g & 63;
  int t = (g >> 6) & 1;
  int b = g >> 7;
  const float* src = Vin + ((size_t)(b * 2 + t)) * CKD + (c << 3);
  float a[8];
  float4 v0 = *(const float4*)src;
  float4 v1 = *(const float4*)(src + 4);
  a[0]=v0.x; a[1]=v0.y; a[2]=v0.z; a[3]=v0.w; a[4]=v1.x; a[5]=v1.y; a[6]=v1.z; a[7]=v1.w;
  float o[8];
#pragma unroll
  for (int ko = 0; ko < 8; ++ko) {
    float sum = T0b[ko];
#pragma unroll
    for (int k = 0; k < 8; ++k) sum += a[k] * T0w[ko * 8 + k];
    o[ko] = sum;
  }
  float* dst = Out + ((size_t)(b * 2 + t)) * CKD + (c << 3);
  *(float4*)dst       = make_float4(o[0], o[1], o[2], o[3]);
  *(float4*)(dst + 4) = make_float4(o[4], o[5], o[6], o[7]);
}

// ---------------------------------------------------------------------------
// Forward truncated DFT (atomic accumulate over t-chunks)
// ---------------------------------------------------------------------------
__global__ __launch_bounds__(256) void k_fdft(
    const float* __restrict__ DD, const float* __restrict__ VD,
    float* __restrict__ XDre, float* __restrict__ XDim,
    float* __restrict__ XVre, float* __restrict__ XVim)
{
  __shared__ float2 tw[2048];  // [f][128]
  int bx = blockIdx.x, j = 1;
  for (;;) {
    int c = (4096 >> j) >> 7; if (c < 1) c = 1;
    if (bx < c) break;
    bx -= c; ++j;
  }
  const int L = 4096 >> j;
  const int t0 = bx << 7;
  const int tcnt = imin(128, L - t0);
  const int b = blockIdx.y;
  const int z = blockIdx.z;
  const int r = (j - 1) * 4 + b;
  const float* src = (z ? VD : DD) +
      ((size_t)(4 * (4096 - (4096 >> (j - 1))) + b * L)) * CKD;
  float* dre = z ? XVre : XDre;
  float* dim_ = z ? XVim : XDim;

  for (int idx = threadIdx.x; idx < 2048; idx += 256) {
    int ff = idx >> 7, tl = idx & 127;
    int t = t0 + tl;
    int m = (2 * ff * t) & (2 * L - 1);
    float xang = (float)m / (float)L;
    tw[idx] = make_float2(cospif(xang), sinpif(xang));
  }
  __syncthreads();

  float ar[16][2] = {};
  float ai[16][2] = {};
  const float* sp = src + (size_t)t0 * CKD + (threadIdx.x << 1);
  for (int tl = 0; tl < tcnt; ++tl) {
    float2 xv = *(const float2*)sp;
    sp += CKD;
#pragma unroll
    for (int ff = 0; ff < 16; ++ff) {
      float2 cs = tw[(ff << 7) + tl];
      ar[ff][0] += xv.x * cs.x; ar[ff][1] += xv.y * cs.x;
      ai[ff][0] -= xv.x * cs.y; ai[ff][1] -= xv.y * cs.y;
    }
  }
  const int i0 = threadIdx.x << 1;
#pragma unroll
  for (int ff = 0; ff < 16; ++ff) {
    size_t bidx = ((size_t)ff * NROWS + r) * CKD + i0;
    atomicAdd(&dre[bidx], ar[ff][0]);
    atomicAdd(&dre[bidx + 1], ar[ff][1]);
    atomicAdd(&dim_[bidx], ai[ff][0]);
    atomicAdd(&dim_[bidx + 1], ai[ff][1]);
  }
}

// ---------------------------------------------------------------------------
// Weight repack to packed bf16: (i,o,f) x6 ->
//   W4b[f][i][o] = uint2( pk2(Ar,Ai), pk2(Br,Bi) )
//   W2b[f][i][o] = uint ( pk2(Cr,Ci) )
// ---------------------------------------------------------------------------
__global__ __launch_bounds__(256) void k_transw6b(
    const float* __restrict__ sAr, const float* __restrict__ sAi,
    const float* __restrict__ sBr, const float* __restrict__ sBi,
    const float* __restrict__ sCr, const float* __restrict__ sCi,
    uint2* __restrict__ W4b, uint32* __restrict__ W2b)
{
  int g = blockIdx.x * 256 + threadIdx.x;  // i*512 + o
  float ar[16], ai[16], br[16], bi[16], cr[16], ci[16];
  const size_t sb = (size_t)g * 16;
#pragma unroll
  for (int q = 0; q < 4; ++q) {
    float4 t;
    t = *(const float4*)(sAr + sb + q * 4); ar[q*4]=t.x; ar[q*4+1]=t.y; ar[q*4+2]=t.z; ar[q*4+3]=t.w;
    t = *(const float4*)(sAi + sb + q * 4); ai[q*4]=t.x; ai[q*4+1]=t.y; ai[q*4+2]=t.z; ai[q*4+3]=t.w;
    t = *(const float4*)(sBr + sb + q * 4); br[q*4]=t.x; br[q*4+1]=t.y; br[q*4+2]=t.z; br[q*4+3]=t.w;
    t = *(const float4*)(sBi + sb + q * 4); bi[q*4]=t.x; bi[q*4+1]=t.y; bi[q*4+2]=t.z; bi[q*4+3]=t.w;
    t = *(const float4*)(sCr + sb + q * 4); cr[q*4]=t.x; cr[q*4+1]=t.y; cr[q*4+2]=t.z; cr[q*4+3]=t.w;
    t = *(const float4*)(sCi + sb + q * 4); ci[q*4]=t.x; ci[q*4+1]=t.y; ci[q*4+2]=t.z; ci[q*4+3]=t.w;
  }
#pragma unroll
  for (int f = 0; f < 16; ++f) {
    size_t e = ((size_t)f << 18) + g;
    W4b[e] = make_uint2(pk2(ar[f], ai[f]), pk2(br[f], bi[f]));
    W2b[e] = pk2(cr[f], ci[f]);
  }
}

// ---------------------------------------------------------------------------
// Pack spectral X -> bf16 MFMA A-matrices:
//   Aud[f][48][2048]: k=4i+c, c=(Dre,Dim,Vre,Vim); rows 44..47 zero
//   Aus[f][48][1024]: k=2i+c, c=(Dre,Dim)
// ---------------------------------------------------------------------------
__global__ __launch_bounds__(256) void k_packA(
    const float* __restrict__ XDre, const float* __restrict__ XDim,
    const float* __restrict__ XVre, const float* __restrict__ XVim,
    unsigned short* __restrict__ Aud, unsigned short* __restrict__ Aus)
{
  int g = blockIdx.x * 256 + threadIdx.x;   // 16 * 48 * 128
  int f = g / 6144;
  int rem = g - f * 6144;
  int r = rem >> 7, iq = rem & 127;         // i = iq*4
  uint4 w0 = make_uint4(0,0,0,0), w1 = w0, wu = w0;
  if (r < NROWS) {
    size_t base = ((size_t)f * NROWS + r) * CKD + (iq << 2);
    float4 dre = *(const float4*)(XDre + base);
    float4 dim_ = *(const float4*)(XDim + base);
    float4 vre = *(const float4*)(XVre + base);
    float4 vim = *(const float4*)(XVim + base);
    w0 = make_uint4(pk2(dre.x, dim_.x), pk2(vre.x, vim.x),
                    pk2(dre.y, dim_.y), pk2(vre.y, vim.y));
    w1 = make_uint4(pk2(dre.z, dim_.z), pk2(vre.z, vim.z),
                    pk2(dre.w, dim_.w), pk2(vre.w, vim.w));
    wu = make_uint4(pk2(dre.x, dim_.x), pk2(dre.y, dim_.y),
                    pk2(dre.z, dim_.z), pk2(dre.w, dim_.w));
  }
  size_t du = ((size_t)f * 48 + r) * 2048 + (iq << 4);
  *(uint4*)(Aud + du)     = w0;
  *(uint4*)(Aud + du + 8) = w1;
  *(uint4*)(Aus + ((size_t)f * 48 + r) * 1024 + (iq << 3)) = wu;
}

// ---------------------------------------------------------------------------
// MFMA channel mix. grid (f=16, oblk=4, isplit=4), 256 thr = 4 waves.
// Per block: o-range 128, i-range 128 (k_ud 512, k_us 256), all 44 rows.
// Wave w covers o-sub w*32 (2 o-tiles of 16) x both comps x ud+us.
// Partials (fp32) -> Part[is][plane][f*44+r][o], planes: udr,udi,usr,usi.
// ---------------------------------------------------------------------------
__global__ __launch_bounds__(256) void k_mixmm(
    const uint2* __restrict__ W4b, const uint32* __restrict__ W2b,
    const unsigned short* __restrict__ Aud, const unsigned short* __restrict__ Aus,
    float* __restrict__ Part)
{
  __shared__ __attribute__((aligned(16))) uint2 sBud[16 * 130];
  __shared__ __attribute__((aligned(16))) uint32 sBus[16 * 132];
  __shared__ __attribute__((aligned(16))) unsigned short sAud[48 * 72];
  __shared__ __attribute__((aligned(16))) unsigned short sAus[48 * 40];

  const int f = blockIdx.x;
  const int o0 = blockIdx.y << 7;
  const int is = blockIdx.z;
  const int i0 = is << 7;
  const int tid = threadIdx.x;
  const int w = tid >> 6, l = tid & 63;
  const int fr = l & 15, fq = l >> 4;
  const int ow0 = w << 5;

  const uint2* gW4 = W4b + ((size_t)f << 18);
  const uint32* gW2 = W2b + ((size_t)f << 18);
  const unsigned short* gAud = Aud + (size_t)f * 48 * 2048;
  const unsigned short* gAus = Aus + (size_t)f * 48 * 1024;

  f32x4 aUd[3][2][2], aUs[3][2][2];
#pragma unroll
  for (int m = 0; m < 3; ++m)
#pragma unroll
    for (int ot = 0; ot < 2; ++ot)
#pragma unroll
      for (int cp = 0; cp < 2; ++cp) {
        aUd[m][ot][cp][0]=0.f; aUd[m][ot][cp][1]=0.f; aUd[m][ot][cp][2]=0.f; aUd[m][ot][cp][3]=0.f;
        aUs[m][ot][cp][0]=0.f; aUs[m][ot][cp][1]=0.f; aUs[m][ot][cp][2]=0.f; aUs[m][ot][cp][3]=0.f;
      }

  for (int ic = 0; ic < 8; ++ic) {
    const int ig = i0 + (ic << 4);
    __syncthreads();
    // stage sBud: 1024 uint4 (16 i x 64 o-pairs)
#pragma unroll
    for (int n = 0; n < 4; ++n) {
      int q = tid + (n << 8);
      int il = q >> 6, op = (q & 63) << 1;
      uint4 v = *(const uint4*)(gW4 + (size_t)(ig + il) * 512 + o0 + op);
      *(uint4*)&sBud[il * 130 + op] = v;
    }
    // stage sBus: 512 uint4 (16 i x 32 o-quads)
#pragma unroll
    for (int n = 0; n < 2; ++n) {
      int q = tid + (n << 8);
      int il = q >> 5, oq = (q & 31) << 2;
      uint4 v = *(const uint4*)(gW2 + (size_t)(ig + il) * 512 + o0 + oq);
      *(uint4*)&sBus[il * 132 + oq] = v;
    }
    // stage sAud: 384 uint4
    {
      int q = tid;
      int m = q >> 3, k8 = (q & 7) << 3;
      uint4 v = *(const uint4*)(gAud + (size_t)m * 2048 + (is << 9) + (ic << 6) + k8);
      *(uint4*)&sAud[m * 72 + k8] = v;
      q = tid + 256;
      if (q < 384) {
        m = q >> 3; k8 = (q & 7) << 3;
        uint4 v2 = *(const uint4*)(gAud + (size_t)m * 2048 + (is << 9) + (ic << 6) + k8);
        *(uint4*)&sAud[m * 72 + k8] = v2;
      }
    }
    // stage sAus: 192 uint4
    if (tid < 192) {
      int m = tid >> 2, k8 = (tid & 3) << 3;
      uint4 v = *(const uint4*)(gAus + (size_t)m * 1024 + (is << 8) + (ic << 5) + k8);
      *(uint4*)&sAus[m * 40 + k8] = v;
    }
    __syncthreads();

    // ud: 2 k-steps of 32
#pragma unroll
    for (int ks = 0; ks < 2; ++ks) {
      bf16x8 af[3];
#pragma unroll
      for (int m = 0; m < 3; ++m)
        af[m] = *(const bf16x8*)&sAud[(m * 16 + fr) * 72 + (ks << 5) + (fq << 3)];
#pragma unroll
      for (int ot = 0; ot < 2; ++ot) {
        int ol = ow0 + (ot << 4) + fr;
        int il = (ks << 3) + (fq << 1);
        uint2 qa = sBud[il * 130 + ol];
        uint2 qb = sBud[(il + 1) * 130 + ol];
        bf16x8 b0 = mk_neghi(qa.x, qa.y, qb.x, qb.y);  // (Ar,-Ai,Br,-Bi)
        bf16x8 b1 = mk_swap(qa.x, qa.y, qb.x, qb.y);   // (Ai,Ar,Bi,Br)
#pragma unroll
        for (int m = 0; m < 3; ++m) {
          aUd[m][ot][0] = __builtin_amdgcn_mfma_f32_16x16x32_bf16(af[m], b0, aUd[m][ot][0], 0, 0, 0);
          aUd[m][ot][1] = __builtin_amdgcn_mfma_f32_16x16x32_bf16(af[m], b1, aUd[m][ot][1], 0, 0, 0);
        }
      }
    }
    // us: 1 k-step of 32
    {
      bf16x8 af[3];
#pragma unroll
      for (int m = 0; m < 3; ++m)
        af[m] = *(const bf16x8*)&sAus[(m * 16 + fr) * 40 + (fq << 3)];
#pragma unroll
      for (int ot = 0; ot < 2; ++ot) {
        int ol = ow0 + (ot << 4) + fr;
        int il = fq << 2;
        uint32 q0 = sBus[(il + 0) * 132 + ol];
        uint32 q1 = sBus[(il + 1) * 132 + ol];
        uint32 q2 = sBus[(il + 2) * 132 + ol];
        uint32 q3 = sBus[(il + 3) * 132 + ol];
        bf16x8 b0 = mk_neghi(q0, q1, q2, q3);          // (Cr,-Ci)
        bf16x8 b1 = mk_swap(q0, q1, q2, q3);           // (Ci,Cr)
#pragma unroll
        for (int m = 0; m < 3; ++m) {
          aUs[m][ot][0] = __builtin_amdgcn_mfma_f32_16x16x32_bf16(af[m], b0, aUs[m][ot][0], 0, 0, 0);
          aUs[m][ot][1] = __builtin_amdgcn_mfma_f32_16x16x32_bf16(af[m], b1, aUs[m][ot][1], 0, 0, 0);
        }
      }
    }
  }

  // epilogue: fp32 partials
  float* P = Part + (size_t)is * 4 * XPLANE;
#pragma unroll
  for (int m = 0; m < 3; ++m) {
#pragma unroll
    for (int reg = 0; reg < 4; ++reg) {
      int r = m * 16 + (fq << 2) + reg;
      if (r < NROWS) {
        size_t rb = ((size_t)f * NROWS + r) * CKD;
#pragma unroll
        for (int ot = 0; ot < 2; ++ot) {
          int col = o0 + ow0 + (ot << 4) + fr;
          P[0 * XPLANE + rb + col] = aUd[m][ot][0][reg];
          P[1 * XPLANE + rb + col] = aUd[m][ot][1][reg];
          P[2 * XPLANE + rb + col] = aUs[m][ot][0][reg];
          P[3 * XPLANE + rb + col] = aUs[m][ot][1][reg];
        }
      }
    }
  }
}

// ---------------------------------------------------------------------------
// Reduce 4 i-split partials -> final spectral UdF/UsF
// ---------------------------------------------------------------------------
__global__ __launch_bounds__(256) void k_reduce4(
    const float* __restrict__ Part,
    float* __restrict__ UdFre, float* __restrict__ UdFim,
    float* __restrict__ UsFre, float* __restrict__ UsFim)
{
  int idx = blockIdx.x * 256 + threadIdx.x;
  if (idx >= XPLANE) return;
  float s0 = 0.f, s1 = 0.f, s2 = 0.f, s3 = 0.f;
#pragma unroll
  for (int is = 0; is < 4; ++is) {
    const float* p = Part + (size_t)is * 4 * XPLANE;
    s0 += p[0 * XPLANE + idx];
    s1 += p[1 * XPLANE + idx];
    s2 += p[2 * XPLANE + idx];
    s3 += p[3 * XPLANE + idx];
  }
  UdFre[idx] = s0; UdFim[idx] = s1; UsFre[idx] = s2; UsFim[idx] = s3;
}

// ---------------------------------------------------------------------------
// Fallback scalar mix (only used if workspace too small for repack arenas)
// ---------------------------------------------------------------------------
__global__ __launch_bounds__(512) void k_mix_fb(
    const float* __restrict__ XDre, const float* __restrict__ XDim,
    const float* __restrict__ XVre, const float* __restrict__ XVim,
    const float* __restrict__ war, const float* __restrict__ wai,
    const float* __restrict__ wbr, const float* __restrict__ wbi,
    const float* __restrict__ wcr, const float* __restrict__ wci,
    float* __restrict__ UdFre, float* __restrict__ UdFim,
    float* __restrict__ UsFre, float* __restrict__ UsFim)
{
  const int f = blockIdx.x;
  const int ot = blockIdx.y;
  const int lane = threadIdx.x & 63;
  const int rg = threadIdx.x >> 6;
  const int rbase = (rg < 4) ? rg * 6 : 24 + (rg - 4) * 5;
  const int rcnt = (rg < 4) ? 6 : 5;
  const int o0 = (ot << 7) + lane;
  __shared__ float4 sx[NROWS * 64];
  float udr[6][2] = {}, udi[6][2] = {}, usr[6][2] = {}, usi[6][2] = {};
  for (int i0 = 0; i0 < 512; i0 += 64) {
    __syncthreads();
    for (int idx = threadIdx.x; idx < NROWS * 64; idx += 512) {
      int r = idx >> 6, il = idx & 63;
      size_t xb = ((size_t)f * NROWS + r) * CKD + i0 + il;
      sx[idx] = make_float4(XDre[xb], XDim[xb], XVre[xb], XVim[xb]);
    }
    __syncthreads();
    for (int ii = 0; ii < 64; ++ii) {
      int i = i0 + ii;
      size_t wo = ((((size_t)i << 9) + o0) << 4) + f;
      float4 wa0 = make_float4(war[wo], wai[wo], wbr[wo], wbi[wo]);
      float2 wc0 = make_float2(wcr[wo], wci[wo]);
      size_t w1 = wo + (64u << 4);
      float4 wa1 = make_float4(war[w1], wai[w1], wbr[w1], wbi[w1]);
      float2 wc1 = make_float2(wcr[w1], wci[w1]);
#pragma unroll
      for (int rr = 0; rr < 6; ++rr) {
        if (rr < rcnt) {
          float4 xv = sx[((rbase + rr) << 6) + ii];
          udr[rr][0] += xv.x * wa0.x - xv.y * wa0.y + xv.z * wa0.z - xv.w * wa0.w;
          udi[rr][0] += xv.x * wa0.y + xv.y * wa0.x + xv.z * wa0.w + xv.w * wa0.z;
          usr[rr][0] += xv.x * wc0.x - xv.y * wc0.y;
          usi[rr][0] += xv.x * wc0.y + xv.y * wc0.x;
          udr[rr][1] += xv.x * wa1.x - xv.y * wa1.y + xv.z * wa1.z - xv.w * wa1.w;
          udi[rr][1] += xv.x * wa1.y + xv.y * wa1.x + xv.z * wa1.w + xv.w * wa1.z;
          usr[rr][1] += xv.x * wc1.x - xv.y * wc1.y;
          usi[rr][1] += xv.x * wc1.y + xv.y * wc1.x;
        }
      }
    }
  }
#pragma unroll
  for (int rr = 0; rr < 6; ++rr) {
    if (rr < rcnt) {
      size_t rb_ = ((size_t)f * NROWS + rbase + rr) * CKD;
      UdFre[rb_ + o0] = udr[rr][0];      UdFre[rb_ + o0 + 64] = udr[rr][1];
      UdFim[rb_ + o0] = udi[rr][0];      UdFim[rb_ + o0 + 64] = udi[rr][1];
      UsFre[rb_ + o0] = usr[rr][0];      UsFre[rb_ + o0 + 64] = usr[rr][1];
      UsFim[rb_ + o0] = usi[rr][0];      UsFim[rb_ + o0 + 64] = usi[rr][1];
    }
  }
}

// ---------------------------------------------------------------------------
// Inverse truncated DFT
// ---------------------------------------------------------------------------
__global__ __launch_bounds__(256) void k_idft(
    const float* __restrict__ UdFre, const float* __restrict__ UdFim,
    const float* __restrict__ UsFre, const float* __restrict__ UsFim,
    float* __restrict__ UdT, float* __restrict__ UsT)
{
  __shared__ float2 tw[128];  // [f][8]
  int bx = blockIdx.x, j = 1;
  for (;;) {
    int c = (4096 >> j) >> 3; if (c < 1) c = 1;
    if (bx < c) break;
    bx -= c; ++j;
  }
  const int L = 4096 >> j;
  const int l = imin(16, (L >> 1) + 1);
  const int t0 = bx << 3;
  const int b = blockIdx.y;
  const int r = (j - 1) * 4 + b;
  if (threadIdx.x < 128) {
    int ff = threadIdx.x >> 3, tl = threadIdx.x & 7;
    int t = t0 + tl;
    int m = (2 * ff * t) & (2 * L - 1);
    float xang = (float)m / (float)L;
    float wgt = (ff == 0 || 2 * ff == L) ? 1.0f : 2.0f;
    float sc = wgt / (float)L;
    tw[threadIdx.x] = make_float2(cospif(xang) * sc, sinpif(xang) * sc);
  }
  __syncthreads();
  const int o = threadIdx.x << 1;
  float2 ud[8], us[8];
#pragma unroll
  for (int tl = 0; tl < 8; ++tl) { ud[tl] = make_float2(0.f, 0.f); us[tl] = make_float2(0.f, 0.f); }
  for (int ff = 0; ff < l; ++ff) {
    size_t bidx = ((size_t)ff * NROWS + r) * CKD + o;
    float2 er = *(const float2*)(UdFre + bidx);
    float2 ei = *(const float2*)(UdFim + bidx);
    float2 sr = *(const float2*)(UsFre + bidx);
    float2 si = *(const float2*)(UsFim + bidx);
#pragma unroll
    for (int tl = 0; tl < 8; ++tl) {
      float2 cs = tw[(ff << 3) + tl];
      ud[tl].x += er.x * cs.x - ei.x * cs.y;
      ud[tl].y += er.y * cs.x - ei.y * cs.y;
      us[tl].x += sr.x * cs.x - si.x * cs.y;
      us[tl].y += sr.y * cs.x - si.y * cs.y;
    }
  }
  int tmax = imin(8, L - t0);
  size_t obase = ((size_t)(4 * (4096 - (4096 >> (j - 1))) + b * L + t0)) * CKD + o;
  for (int tl = 0; tl < tmax; ++tl) {
    *(float2*)(UdT + obase + (size_t)tl * CKD) = ud[tl];
    *(float2*)(UsT + obase + (size_t)tl * CKD) = us[tl];
  }
}

// ---------------------------------------------------------------------------
// Reconstruction
// ---------------------------------------------------------------------------
__global__ __launch_bounds__(256) void k_recon(
    const float* __restrict__ Vcur, const float* __restrict__ UdT,
    const float* __restrict__ UsT, const float* __restrict__ rc_e,
    const float* __restrict__ rc_o, float* __restrict__ Vnext,
    int Lc, int abase)
{
  __shared__ float Re[128], Ro[128];
  if (threadIdx.x < 128) Re[threadIdx.x] = rc_e[threadIdx.x];
  else Ro[threadIdx.x - 128] = rc_o[threadIdx.x - 128];
  __syncthreads();
  int g = blockIdx.x * 256 + threadIdx.x;
  if (g >= 4 * Lc * 64) return;
  int c = g & 63;
  int s = (g >> 6) % Lc;
  int b = g / (Lc << 6);
  size_t vrow = ((size_t)b * Lc + s) * CKD + (c << 3);
  size_t arow = ((size_t)abase + (size_t)b * Lc + s) * CKD + (c << 3);
  float a[16];
  {
    float4 t0_ = *(const float4*)(Vcur + vrow);
    float4 t1_ = *(const float4*)(Vcur + vrow + 4);
    float4 u0 = *(const float4*)(UsT + arow);
    float4 u1 = *(const float4*)(UsT + arow + 4);
    a[0]=t0_.x+u0.x; a[1]=t0_.y+u0.y; a[2]=t0_.z+u0.z; a[3]=t0_.w+u0.w;
    a[4]=t1_.x+u1.x; a[5]=t1_.y+u1.y; a[6]=t1_.z+u1.z; a[7]=t1_.w+u1.w;
    float4 d0 = *(const float4*)(UdT + arow);
    float4 d1 = *(const float4*)(UdT + arow + 4);
    a[8]=d0.x; a[9]=d0.y; a[10]=d0.z; a[11]=d0.w;
    a[12]=d1.x; a[13]=d1.y; a[14]=d1.z; a[15]=d1.w;
  }
  float xe[8] = {}, xo[8] = {};
#pragma unroll
  for (int m = 0; m < 16; ++m)
#pragma unroll
    for (int k = 0; k < 8; ++k) {
      xe[k] += a[m] * Re[m * 8 + k];
      xo[k] += a[m] * Ro[m * 8 + k];
    }
  size_t orow = ((size_t)b * (Lc << 1) + (s << 1)) * CKD + (c << 3);
  *(float4*)(Vnext + orow)           = make_float4(xe[0], xe[1], xe[2], xe[3]);
  *(float4*)(Vnext + orow + 4)       = make_float4(xe[4], xe[5], xe[6], xe[7]);
  *(float4*)(Vnext + orow + CKD)     = make_float4(xo[0], xo[1], xo[2], xo[3]);
  *(float4*)(Vnext + orow + CKD + 4) = make_float4(xo[4], xo[5], xo[6], xo[7]);
}

// ---------------------------------------------------------------------------
extern "C" void kernel_launch(void* const* d_in, const int* in_sizes, int n_in,
                              void* d_out, int out_size, void* d_ws, size_t ws_size,
                              hipStream_t stream)
{
  const float* x     = (const float*)d_in[0];
  const float* Lk0_w = (const float*)d_in[1];
  const float* Lk0_b = (const float*)d_in[2];
  const float* Lk1_w = (const float*)d_in[3];
  const float* Lk1_b = (const float*)d_in[4];
  const float* T0_w  = (const float*)d_in[5];
  const float* T0_b  = (const float*)d_in[6];
  const float* Ar = (const float*)d_in[7];
  const float* Ai = (const float*)d_in[8];
  const float* Br = (const float*)d_in[9];
  const float* Bi = (const float*)d_in[10];
  const float* Cr = (const float*)d_in[11];
  const float* Ci = (const float*)d_in[12];
  const float* ec_s = (const float*)d_in[13];
  const float* ec_d = (const float*)d_in[14];
  const float* rc_e = (const float*)d_in[15];
  const float* rc_o = (const float*)d_in[16];
  float* out = (float*)d_out;

  // workspace layout (floats)
  float* w = (float*)d_ws;
  float* V0 = w;   w += (size_t)4 * 4096 * 512;  // RA
  float* VD = w;   w += (size_t)4 * 4094 * 512;  // aliased as UsT
  float* DD = w;   w += (size_t)4 * 4094 * 512;  // aliased as UdT; late: Cb
  float* RB = w;   w += (size_t)4 * 4096 * 512;  // early: Xb; mid: Part (16*XPLANE)
  float* XDre = w; w += XPLANE;
  float* XDim = w; w += XPLANE;
  float* XVre = w; w += XPLANE;
  float* XVim = w; w += XPLANE;
  float* UdFre = w; w += XPLANE;   // early: Wb0/Wb1 bf16
  float* UdFim = w; w += XPLANE;
  float* UsFre = w; w += XPLANE;
  float* UsFim = w; w += XPLANE;
  float* WT = w;
  float* RA = V0;
  float* UdT = DD;
  float* UsT = VD;
  float* Part = RB;                // 16*XPLANE = 5.77M <= 8.39M

  unsigned short* Xb  = (unsigned short*)RB;
  unsigned short* Cb  = (unsigned short*)DD;
  unsigned short* Wb0 = (unsigned short*)UdFre;
  unsigned short* Wb1 = (unsigned short*)UdFre;

  const size_t BASE_FLOATS = 36421632ull;
  const size_t WT_FLOATS   = 25165824ull;
  if (ws_size < BASE_FLOATS * 4) return;
  const bool use_wt = ws_size >= (BASE_FLOATS + WT_FLOATS) * 4;
  uint2*  W4b = (uint2*)WT;                              // 8,388,608 floats
  uint32* W2b = (uint32*)(WT + 8388608ull);              // 4,194,304 floats
  unsigned short* AudP = (unsigned short*)(WT + 12582912ull);  // 786,432 floats
  unsigned short* AusP = (unsigned short*)(WT + 13369344ull);  // 393,216 floats

  // 1. bf16 converts + Lk0 GEMM (MFMA)
  k_cvt_x<<<dim3(4096), dim3(256), 0, stream>>>(x, Xb);
  k_cvt_gen<<<dim3(128), dim3(256), 0, stream>>>(Lk0_w, Wb0);
  k_gemm_bf16<<<dim3(128, 4), dim3(256), 0, stream>>>(Xb, Wb0, Lk0_b, V0);

  // 2. decomposition levels j = 1..11
  for (int j = 1; j <= 11; ++j) {
    int Lout = 4096 >> j;
    int pin = 4096 >> (j - 1);
    const float* vin = (j == 1)
        ? V0
        : VD + (size_t)4 * (4096 - (4096 >> (j - 2))) * 512;
    size_t base = (size_t)4 * (4096 - (4096 >> (j - 1))) * 512;
    k_decomp<<<dim3(Lout), dim3(256), 0, stream>>>(vin, ec_s, ec_d,
                                                   DD + base, VD + base, Lout, pin);
  }

  // 3. T0 on v_11
  k_t0<<<dim3(2), dim3(256), 0, stream>>>(VD + (size_t)4 * 4092 * 512, T0_w, T0_b, RA);

  // 4. zero X accumulators
  hipMemsetAsync(XDre, 0, (size_t)4 * XPLANE * 4, stream);

  // 5. weight repack to packed bf16 [f][i][o]
  if (use_wt)
    k_transw6b<<<dim3(1024), dim3(256), 0, stream>>>(Ar, Ai, Br, Bi, Cr, Ci, W4b, W2b);

  // 6. forward DFTs of all levels
  k_fdft<<<dim3(37, 4, 2), dim3(256), 0, stream>>>(DD, VD, XDre, XDim, XVre, XVim);

  if (use_wt) {
    // 7. pack A matrices, MFMA mix, reduce
    k_packA<<<dim3(384), dim3(256), 0, stream>>>(XDre, XDim, XVre, XVim, AudP, AusP);
    k_mixmm<<<dim3(16, 4, 4), dim3(256), 0, stream>>>(W4b, W2b, AudP, AusP, Part);
    k_reduce4<<<dim3((XPLANE + 255) / 256), dim3(256), 0, stream>>>(
        Part, UdFre, UdFim, UsFre, UsFim);
  } else {
    k_mix_fb<<<dim3(16, 4), dim3(512), 0, stream>>>(
        XDre, XDim, XVre, XVim, Ar, Ai, Br, Bi, Cr, Ci,
        UdFre, UdFim, UsFre, UsFim);
  }

  // 8. inverse DFTs into time-domain Ud/Us arenas
  k_idft<<<dim3(513, 4), dim3(256), 0, stream>>>(UdFre, UdFim, UsFre, UsFim, UdT, UsT);

  // 9. reconstruction j = 11..1
  float* cur = RA;
  float* nxt = RB;
  for (int j = 11; j >= 1; --j) {
    int Lc = 4096 >> j;
    int abase = 4 * (4096 - (4096 >> (j - 1)));
    k_recon<<<dim3(Lc), dim3(256), 0, stream>>>(cur, UdT, UsT, rc_e, rc_o, nxt, Lc, abase);
    float* t = cur; cur = nxt; nxt = t;
  }

  // 10. Lk1 GEMM (MFMA)
  k_cvt_c<<<dim3(3072), dim3(256), 0, stream>>>(cur, Cb);
  k_cvt_gen<<<dim3(128), dim3(256), 0, stream>>>(Lk1_w, Wb1);
  k_gemm_bf16<<<dim3(96, 4), dim3(256), 0, stream>>>(Cb, Wb1, Lk1_b, out);
}

// Round 6
// 512.779 us; speedup vs baseline: 1.7644x; 1.0195x over previous
//
#include <hip/hip_runtime.h>

#define CKD 512
#define NROWS 44
#define XPLANE 360448  // 16*44*512

static __device__ __forceinline__ int imin(int a, int b) { return a < b ? a : b; }

typedef short bf16x8 __attribute__((ext_vector_type(8)));
typedef float f32x4 __attribute__((ext_vector_type(4)));
typedef unsigned int uint32;

// RNE float->bf16 pack of two floats into one u32 (lo = a, hi = b)
static __device__ __forceinline__ unsigned int pk2(float a, float b) {
  unsigned int ua = __float_as_uint(a), ub = __float_as_uint(b);
  ua = (ua + 0x7fffu + ((ua >> 16) & 1u)) >> 16;
  ub = (ub + 0x7fffu + ((ub >> 16) & 1u)) >> 16;
  return ua | (ub << 16);
}

static __device__ __forceinline__ uint32 ror16(uint32 q) { return (q >> 16) | (q << 16); }

static __device__ __forceinline__ bf16x8 mk_neghi(uint32 q0, uint32 q1, uint32 q2, uint32 q3) {
  union { uint32 u[4]; bf16x8 h; } t;
  t.u[0] = q0 ^ 0x80000000u; t.u[1] = q1 ^ 0x80000000u;
  t.u[2] = q2 ^ 0x80000000u; t.u[3] = q3 ^ 0x80000000u;
  return t.h;
}
static __device__ __forceinline__ bf16x8 mk_swap(uint32 q0, uint32 q1, uint32 q2, uint32 q3) {
  union { uint32 u[4]; bf16x8 h; } t;
  t.u[0] = ror16(q0); t.u[1] = ror16(q1); t.u[2] = ror16(q2); t.u[3] = ror16(q3);
  return t.h;
}

// ---------------------------------------------------------------------------
// Convert x (4,3072,512) fp32 -> Xb (4,4096,512) bf16 with wraparound pad
// ---------------------------------------------------------------------------
__global__ __launch_bounds__(256) void k_cvt_x(
    const float* __restrict__ src, unsigned short* __restrict__ dst)
{
  int g = blockIdx.x * 256 + threadIdx.x;      // 16384*64
  int row = g >> 6, c8 = (g & 63) << 3;
  int b = row >> 12, t = row & 4095;
  if (t >= 3072) t -= 3072;
  const float* s = src + ((size_t)(b * 3072 + t) << 9) + c8;
  float4 v0 = *(const float4*)s;
  float4 v1 = *(const float4*)(s + 4);
  uint4 o = make_uint4(pk2(v0.x, v0.y), pk2(v0.z, v0.w),
                       pk2(v1.x, v1.y), pk2(v1.z, v1.w));
  *(uint4*)(dst + ((size_t)row << 9) + c8) = o;
}

__global__ __launch_bounds__(256) void k_cvt_gen(
    const float* __restrict__ src, unsigned short* __restrict__ dst)
{
  int g = blockIdx.x * 256 + threadIdx.x;
  const float* s = src + ((size_t)g << 3);
  float4 v0 = *(const float4*)s;
  float4 v1 = *(const float4*)(s + 4);
  uint4 o = make_uint4(pk2(v0.x, v0.y), pk2(v0.z, v0.w),
                       pk2(v1.x, v1.y), pk2(v1.z, v1.w));
  *(uint4*)(dst + ((size_t)g << 3)) = o;
}

__global__ __launch_bounds__(256) void k_cvt_c(
    const float* __restrict__ src, unsigned short* __restrict__ dst)
{
  int g = blockIdx.x * 256 + threadIdx.x;      // 12288*64
  int row = g >> 6, c8 = (g & 63) << 3;
  int b = row / 3072, t = row - b * 3072;
  const float* s = src + ((size_t)((b << 12) + t) << 9) + c8;
  float4 v0 = *(const float4*)s;
  float4 v1 = *(const float4*)(s + 4);
  uint4 o = make_uint4(pk2(v0.x, v0.y), pk2(v0.z, v0.w),
                       pk2(v1.x, v1.y), pk2(v1.z, v1.w));
  *(uint4*)(dst + ((size_t)row << 9) + c8) = o;
}

// ---------------------------------------------------------------------------
// bf16 MFMA GEMM: Out[m][n] = sum_k A[m][k]*W[n][k] + bias[n], K=N=512
// ---------------------------------------------------------------------------
__global__ __launch_bounds__(256) void k_gemm_bf16(
    const unsigned short* __restrict__ A, const unsigned short* __restrict__ W,
    const float* __restrict__ bias, float* __restrict__ Out)
{
  __shared__ unsigned short As[128 * 40];
  __shared__ unsigned short Bs[128 * 40];
  const int tid = threadIdx.x;
  const int row = tid >> 1, half = tid & 1;
  const int bm0 = blockIdx.x << 7, bn0 = blockIdx.y << 7;
  const int wv = tid >> 6, l = tid & 63;
  const int wm0 = (wv & 1) << 6, wn0 = (wv >> 1) << 6;
  const int fr = l & 15, fq = l >> 4;

  const unsigned short* Ap = A + (size_t)(bm0 + row) * CKD + half * 16;
  const unsigned short* Wp = W + (size_t)(bn0 + row) * CKD + half * 16;

  f32x4 acc[4][4];
#pragma unroll
  for (int mt = 0; mt < 4; ++mt)
#pragma unroll
    for (int nt = 0; nt < 4; ++nt) {
      acc[mt][nt][0] = 0.f; acc[mt][nt][1] = 0.f;
      acc[mt][nt][2] = 0.f; acc[mt][nt][3] = 0.f;
    }

  for (int k0 = 0; k0 < CKD; k0 += 32) {
    uint4 av0 = *(const uint4*)(Ap + k0);
    uint4 av1 = *(const uint4*)(Ap + k0 + 8);
    uint4 bv0 = *(const uint4*)(Wp + k0);
    uint4 bv1 = *(const uint4*)(Wp + k0 + 8);
    __syncthreads();
    *(uint4*)&As[row * 40 + half * 16]     = av0;
    *(uint4*)&As[row * 40 + half * 16 + 8] = av1;
    *(uint4*)&Bs[row * 40 + half * 16]     = bv0;
    *(uint4*)&Bs[row * 40 + half * 16 + 8] = bv1;
    __syncthreads();
    bf16x8 af[4], bfr[4];
#pragma unroll
    for (int mt = 0; mt < 4; ++mt)
      af[mt] = *(const bf16x8*)&As[(wm0 + mt * 16 + fr) * 40 + fq * 8];
#pragma unroll
    for (int nt = 0; nt < 4; ++nt)
      bfr[nt] = *(const bf16x8*)&Bs[(wn0 + nt * 16 + fr) * 40 + fq * 8];
#pragma unroll
    for (int mt = 0; mt < 4; ++mt)
#pragma unroll
      for (int nt = 0; nt < 4; ++nt)
        acc[mt][nt] = __builtin_amdgcn_mfma_f32_16x16x32_bf16(
            af[mt], bfr[nt], acc[mt][nt], 0, 0, 0);
  }

#pragma unroll
  for (int nt = 0; nt < 4; ++nt) {
    int col = bn0 + wn0 + nt * 16 + fr;
    float bv = bias[col];
#pragma unroll
    for (int mt = 0; mt < 4; ++mt) {
      int r0 = bm0 + wm0 + mt * 16 + fq * 4;
#pragma unroll
      for (int rg = 0; rg < 4; ++rg)
        Out[(size_t)(r0 + rg) * CKD + col] = acc[mt][nt][rg] + bv;
    }
  }
}

// ---------------------------------------------------------------------------
// Fused decomposition tree: one block stages 16 input rows in LDS and emits
// NL levels (8,4,2,1 output rows) of d/v to the global arenas.
// grid = (pin/16, 4 batches). j0 = first level, pin = rows/batch of Vin.
// ---------------------------------------------------------------------------
__global__ __launch_bounds__(256) void k_decomp_tree(
    const float* __restrict__ Vin, const float* __restrict__ ec_s,
    const float* __restrict__ ec_d, float* __restrict__ DD,
    float* __restrict__ VD, int j0, int NL, int pin)
{
  __shared__ float Es[128], Ed[128];
  __shared__ float bufA[16 * 512];
  __shared__ float bufB[8 * 512];
  const int tid = threadIdx.x;
  if (tid < 128) Es[tid] = ec_s[tid];
  else Ed[tid - 128] = ec_d[tid - 128];
  const int b = blockIdx.y;
  const int t0 = blockIdx.x << 4;

  const float* src = Vin + ((size_t)b * pin + t0) * CKD;
  for (int q = tid; q < 16 * 128; q += 256) {
    int rr = q >> 7, c4 = (q & 127) << 2;
    *(float4*)&bufA[rr * 512 + c4] = *(const float4*)(src + (size_t)rr * CKD + c4);
  }
  __syncthreads();

  float* rd = bufA;
  float* wr = bufB;
  for (int lv = 0; lv < NL; ++lv) {
    const int j = j0 + lv;
    const int Lout = 4096 >> j;
    const int rows = 8 >> lv;
    const int sb = t0 >> (lv + 1);
    const size_t base = 4ull * (4096 - (4096 >> (j - 1))) * CKD;
    float* Dp = DD + base;
    float* Vp = VD + base;
    for (int task = tid; task < rows * 64; task += 256) {
      int s = task >> 6, c = task & 63;
      const float* r0p = rd + (2 * s) * 512 + (c << 3);
      float a[16];
      float4 v0 = *(const float4*)r0p;
      float4 v1 = *(const float4*)(r0p + 4);
      float4 v2 = *(const float4*)(r0p + 512);
      float4 v3 = *(const float4*)(r0p + 516);
      a[0]=v0.x; a[1]=v0.y; a[2]=v0.z; a[3]=v0.w; a[4]=v1.x; a[5]=v1.y; a[6]=v1.z; a[7]=v1.w;
      a[8]=v2.x; a[9]=v2.y; a[10]=v2.z; a[11]=v2.w; a[12]=v3.x; a[13]=v3.y; a[14]=v3.z; a[15]=v3.w;
      float dv[8] = {}, vv[8] = {};
#pragma unroll
      for (int m = 0; m < 16; ++m)
#pragma unroll
        for (int k = 0; k < 8; ++k) {
          dv[k] += a[m] * Ed[m * 8 + k];
          vv[k] += a[m] * Es[m * 8 + k];
        }
      size_t orow = ((size_t)b * Lout + sb + s) * CKD + (c << 3);
      *(float4*)(Dp + orow)     = make_float4(dv[0], dv[1], dv[2], dv[3]);
      *(float4*)(Dp + orow + 4) = make_float4(dv[4], dv[5], dv[6], dv[7]);
      *(float4*)(Vp + orow)     = make_float4(vv[0], vv[1], vv[2], vv[3]);
      *(float4*)(Vp + orow + 4) = make_float4(vv[4], vv[5], vv[6], vv[7]);
      if (lv + 1 < NL) {
        float* wp = wr + s * 512 + (c << 3);
        *(float4*)wp       = make_float4(vv[0], vv[1], vv[2], vv[3]);
        *(float4*)(wp + 4) = make_float4(vv[4], vv[5], vv[6], vv[7]);
      }
    }
    __syncthreads();
    float* t = rd; rd = wr; wr = t;
  }
}

// ---------------------------------------------------------------------------
// T0
// ---------------------------------------------------------------------------
__global__ __launch_bounds__(256) void k_t0(
    const float* __restrict__ Vin, const float* __restrict__ T0w,
    const float* __restrict__ T0b, float* __restrict__ Out)
{
  int g = blockIdx.x * 256 + threadIdx.x;
  if (g >= 4 * 2 * 64) return;
  int c = g & 63;
  int t = (g >> 6) & 1;
  int b = g >> 7;
  const float* src = Vin + ((size_t)(b * 2 + t)) * CKD + (c << 3);
  float a[8];
  float4 v0 = *(const float4*)src;
  float4 v1 = *(const float4*)(src + 4);
  a[0]=v0.x; a[1]=v0.y; a[2]=v0.z; a[3]=v0.w; a[4]=v1.x; a[5]=v1.y; a[6]=v1.z; a[7]=v1.w;
  float o[8];
#pragma unroll
  for (int ko = 0; ko < 8; ++ko) {
    float sum = T0b[ko];
#pragma unroll
    for (int k = 0; k < 8; ++k) sum += a[k] * T0w[ko * 8 + k];
    o[ko] = sum;
  }
  float* dst = Out + ((size_t)(b * 2 + t)) * CKD + (c << 3);
  *(float4*)dst       = make_float4(o[0], o[1], o[2], o[3]);
  *(float4*)(dst + 4) = make_float4(o[4], o[5], o[6], o[7]);
}

// ---------------------------------------------------------------------------
// Forward truncated DFT, t-chunk = 64, software prefetch, atomic accumulate
// ---------------------------------------------------------------------------
__global__ __launch_bounds__(256) void k_fdft(
    const float* __restrict__ DD, const float* __restrict__ VD,
    float* __restrict__ XDre, float* __restrict__ XDim,
    float* __restrict__ XVre, float* __restrict__ XVim)
{
  __shared__ float2 tw[1024];  // [f][64]
  int bx = blockIdx.x, j = 1;
  for (;;) {
    int c = (4096 >> j) >> 6; if (c < 1) c = 1;
    if (bx < c) break;
    bx -= c; ++j;
  }
  const int L = 4096 >> j;
  const int t0 = bx << 6;
  const int tcnt = imin(64, L - t0);
  const int b = blockIdx.y;
  const int z = blockIdx.z;
  const int r = (j - 1) * 4 + b;
  const float* src = (z ? VD : DD) +
      ((size_t)(4 * (4096 - (4096 >> (j - 1))) + b * L)) * CKD;
  float* dre = z ? XVre : XDre;
  float* dim_ = z ? XVim : XDim;

  for (int idx = threadIdx.x; idx < 1024; idx += 256) {
    int ff = idx >> 6, tl = idx & 63;
    int t = t0 + tl;
    int m = (2 * ff * t) & (2 * L - 1);
    float xang = (float)m / (float)L;
    tw[idx] = make_float2(cospif(xang), sinpif(xang));
  }
  __syncthreads();

  float ar[16][2] = {};
  float ai[16][2] = {};
  const float* sp = src + (size_t)t0 * CKD + (threadIdx.x << 1);
  float2 nxt = *(const float2*)sp;
  for (int tl = 0; tl < tcnt; ++tl) {
    float2 xv = nxt;
    if (tl + 1 < tcnt) nxt = *(const float2*)(sp + (size_t)(tl + 1) * CKD);
#pragma unroll
    for (int ff = 0; ff < 16; ++ff) {
      float2 cs = tw[(ff << 6) + tl];
      ar[ff][0] += xv.x * cs.x; ar[ff][1] += xv.y * cs.x;
      ai[ff][0] -= xv.x * cs.y; ai[ff][1] -= xv.y * cs.y;
    }
  }
  const int i0 = threadIdx.x << 1;
#pragma unroll
  for (int ff = 0; ff < 16; ++ff) {
    size_t bidx = ((size_t)ff * NROWS + r) * CKD + i0;
    atomicAdd(&dre[bidx], ar[ff][0]);
    atomicAdd(&dre[bidx + 1], ar[ff][1]);
    atomicAdd(&dim_[bidx], ai[ff][0]);
    atomicAdd(&dim_[bidx + 1], ai[ff][1]);
  }
}

// ---------------------------------------------------------------------------
// Weight repack to packed bf16
// ---------------------------------------------------------------------------
__global__ __launch_bounds__(256) void k_transw6b(
    const float* __restrict__ sAr, const float* __restrict__ sAi,
    const float* __restrict__ sBr, const float* __restrict__ sBi,
    const float* __restrict__ sCr, const float* __restrict__ sCi,
    uint2* __restrict__ W4b, uint32* __restrict__ W2b)
{
  int g = blockIdx.x * 256 + threadIdx.x;  // i*512 + o
  float ar[16], ai[16], br[16], bi[16], cr[16], ci[16];
  const size_t sb = (size_t)g * 16;
#pragma unroll
  for (int q = 0; q < 4; ++q) {
    float4 t;
    t = *(const float4*)(sAr + sb + q * 4); ar[q*4]=t.x; ar[q*4+1]=t.y; ar[q*4+2]=t.z; ar[q*4+3]=t.w;
    t = *(const float4*)(sAi + sb + q * 4); ai[q*4]=t.x; ai[q*4+1]=t.y; ai[q*4+2]=t.z; ai[q*4+3]=t.w;
    t = *(const float4*)(sBr + sb + q * 4); br[q*4]=t.x; br[q*4+1]=t.y; br[q*4+2]=t.z; br[q*4+3]=t.w;
    t = *(const float4*)(sBi + sb + q * 4); bi[q*4]=t.x; bi[q*4+1]=t.y; bi[q*4+2]=t.z; bi[q*4+3]=t.w;
    t = *(const float4*)(sCr + sb + q * 4); cr[q*4]=t.x; cr[q*4+1]=t.y; cr[q*4+2]=t.z; cr[q*4+3]=t.w;
    t = *(const float4*)(sCi + sb + q * 4); ci[q*4]=t.x; ci[q*4+1]=t.y; ci[q*4+2]=t.z; ci[q*4+3]=t.w;
  }
#pragma unroll
  for (int f = 0; f < 16; ++f) {
    size_t e = ((size_t)f << 18) + g;
    W4b[e] = make_uint2(pk2(ar[f], ai[f]), pk2(br[f], bi[f]));
    W2b[e] = pk2(cr[f], ci[f]);
  }
}

// ---------------------------------------------------------------------------
// Pack spectral X -> bf16 MFMA A-matrices
// ---------------------------------------------------------------------------
__global__ __launch_bounds__(256) void k_packA(
    const float* __restrict__ XDre, const float* __restrict__ XDim,
    const float* __restrict__ XVre, const float* __restrict__ XVim,
    unsigned short* __restrict__ Aud, unsigned short* __restrict__ Aus)
{
  int g = blockIdx.x * 256 + threadIdx.x;   // 16 * 48 * 128
  int f = g / 6144;
  int rem = g - f * 6144;
  int r = rem >> 7, iq = rem & 127;
  uint4 w0 = make_uint4(0,0,0,0), w1 = w0, wu = w0;
  if (r < NROWS) {
    size_t base = ((size_t)f * NROWS + r) * CKD + (iq << 2);
    float4 dre = *(const float4*)(XDre + base);
    float4 dim_ = *(const float4*)(XDim + base);
    float4 vre = *(const float4*)(XVre + base);
    float4 vim = *(const float4*)(XVim + base);
    w0 = make_uint4(pk2(dre.x, dim_.x), pk2(vre.x, vim.x),
                    pk2(dre.y, dim_.y), pk2(vre.y, vim.y));
    w1 = make_uint4(pk2(dre.z, dim_.z), pk2(vre.z, vim.z),
                    pk2(dre.w, dim_.w), pk2(vre.w, vim.w));
    wu = make_uint4(pk2(dre.x, dim_.x), pk2(dre.y, dim_.y),
                    pk2(dre.z, dim_.z), pk2(dre.w, dim_.w));
  }
  size_t du = ((size_t)f * 48 + r) * 2048 + (iq << 4);
  *(uint4*)(Aud + du)     = w0;
  *(uint4*)(Aud + du + 8) = w1;
  *(uint4*)(Aus + ((size_t)f * 48 + r) * 1024 + (iq << 3)) = wu;
}

// ---------------------------------------------------------------------------
// MFMA channel mix; partials -> Part[is][plane][f*44+r][o]
// ---------------------------------------------------------------------------
__global__ __launch_bounds__(256) void k_mixmm(
    const uint2* __restrict__ W4b, const uint32* __restrict__ W2b,
    const unsigned short* __restrict__ Aud, const unsigned short* __restrict__ Aus,
    float* __restrict__ Part)
{
  __shared__ __attribute__((aligned(16))) uint2 sBud[16 * 130];
  __shared__ __attribute__((aligned(16))) uint32 sBus[16 * 132];
  __shared__ __attribute__((aligned(16))) unsigned short sAud[48 * 72];
  __shared__ __attribute__((aligned(16))) unsigned short sAus[48 * 40];

  const int f = blockIdx.x;
  const int o0 = blockIdx.y << 7;
  const int is = blockIdx.z;
  const int i0 = is << 7;
  const int tid = threadIdx.x;
  const int w = tid >> 6, l = tid & 63;
  const int fr = l & 15, fq = l >> 4;
  const int ow0 = w << 5;

  const uint2* gW4 = W4b + ((size_t)f << 18);
  const uint32* gW2 = W2b + ((size_t)f << 18);
  const unsigned short* gAud = Aud + (size_t)f * 48 * 2048;
  const unsigned short* gAus = Aus + (size_t)f * 48 * 1024;

  f32x4 aUd[3][2][2], aUs[3][2][2];
#pragma unroll
  for (int m = 0; m < 3; ++m)
#pragma unroll
    for (int ot = 0; ot < 2; ++ot)
#pragma unroll
      for (int cp = 0; cp < 2; ++cp) {
        aUd[m][ot][cp][0]=0.f; aUd[m][ot][cp][1]=0.f; aUd[m][ot][cp][2]=0.f; aUd[m][ot][cp][3]=0.f;
        aUs[m][ot][cp][0]=0.f; aUs[m][ot][cp][1]=0.f; aUs[m][ot][cp][2]=0.f; aUs[m][ot][cp][3]=0.f;
      }

  for (int ic = 0; ic < 8; ++ic) {
    const int ig = i0 + (ic << 4);
    __syncthreads();
#pragma unroll
    for (int n = 0; n < 4; ++n) {
      int q = tid + (n << 8);
      int il = q >> 6, op = (q & 63) << 1;
      uint4 v = *(const uint4*)(gW4 + (size_t)(ig + il) * 512 + o0 + op);
      *(uint4*)&sBud[il * 130 + op] = v;
    }
#pragma unroll
    for (int n = 0; n < 2; ++n) {
      int q = tid + (n << 8);
      int il = q >> 5, oq = (q & 31) << 2;
      uint4 v = *(const uint4*)(gW2 + (size_t)(ig + il) * 512 + o0 + oq);
      *(uint4*)&sBus[il * 132 + oq] = v;
    }
    {
      int q = tid;
      int m = q >> 3, k8 = (q & 7) << 3;
      uint4 v = *(const uint4*)(gAud + (size_t)m * 2048 + (is << 9) + (ic << 6) + k8);
      *(uint4*)&sAud[m * 72 + k8] = v;
      q = tid + 256;
      if (q < 384) {
        m = q >> 3; k8 = (q & 7) << 3;
        uint4 v2 = *(const uint4*)(gAud + (size_t)m * 2048 + (is << 9) + (ic << 6) + k8);
        *(uint4*)&sAud[m * 72 + k8] = v2;
      }
    }
    if (tid < 192) {
      int m = tid >> 2, k8 = (tid & 3) << 3;
      uint4 v = *(const uint4*)(gAus + (size_t)m * 1024 + (is << 8) + (ic << 5) + k8);
      *(uint4*)&sAus[m * 40 + k8] = v;
    }
    __syncthreads();

#pragma unroll
    for (int ks = 0; ks < 2; ++ks) {
      bf16x8 af[3];
#pragma unroll
      for (int m = 0; m < 3; ++m)
        af[m] = *(const bf16x8*)&sAud[(m * 16 + fr) * 72 + (ks << 5) + (fq << 3)];
#pragma unroll
      for (int ot = 0; ot < 2; ++ot) {
        int ol = ow0 + (ot << 4) + fr;
        int il = (ks << 3) + (fq << 1);
        uint2 qa = sBud[il * 130 + ol];
        uint2 qb = sBud[(il + 1) * 130 + ol];
        bf16x8 b0 = mk_neghi(qa.x, qa.y, qb.x, qb.y);
        bf16x8 b1 = mk_swap(qa.x, qa.y, qb.x, qb.y);
#pragma unroll
        for (int m = 0; m < 3; ++m) {
          aUd[m][ot][0] = __builtin_amdgcn_mfma_f32_16x16x32_bf16(af[m], b0, aUd[m][ot][0], 0, 0, 0);
          aUd[m][ot][1] = __builtin_amdgcn_mfma_f32_16x16x32_bf16(af[m], b1, aUd[m][ot][1], 0, 0, 0);
        }
      }
    }
    {
      bf16x8 af[3];
#pragma unroll
      for (int m = 0; m < 3; ++m)
        af[m] = *(const bf16x8*)&sAus[(m * 16 + fr) * 40 + (fq << 3)];
#pragma unroll
      for (int ot = 0; ot < 2; ++ot) {
        int ol = ow0 + (ot << 4) + fr;
        int il = fq << 2;
        uint32 q0 = sBus[(il + 0) * 132 + ol];
        uint32 q1 = sBus[(il + 1) * 132 + ol];
        uint32 q2 = sBus[(il + 2) * 132 + ol];
        uint32 q3 = sBus[(il + 3) * 132 + ol];
        bf16x8 b0 = mk_neghi(q0, q1, q2, q3);
        bf16x8 b1 = mk_swap(q0, q1, q2, q3);
#pragma unroll
        for (int m = 0; m < 3; ++m) {
          aUs[m][ot][0] = __builtin_amdgcn_mfma_f32_16x16x32_bf16(af[m], b0, aUs[m][ot][0], 0, 0, 0);
          aUs[m][ot][1] = __builtin_amdgcn_mfma_f32_16x16x32_bf16(af[m], b1, aUs[m][ot][1], 0, 0, 0);
        }
      }
    }
  }

  float* P = Part + (size_t)is * 4 * XPLANE;
#pragma unroll
  for (int m = 0; m < 3; ++m) {
#pragma unroll
    for (int reg = 0; reg < 4; ++reg) {
      int r = m * 16 + (fq << 2) + reg;
      if (r < NROWS) {
        size_t rb = ((size_t)f * NROWS + r) * CKD;
#pragma unroll
        for (int ot = 0; ot < 2; ++ot) {
          int col = o0 + ow0 + (ot << 4) + fr;
          P[0 * XPLANE + rb + col] = aUd[m][ot][0][reg];
          P[1 * XPLANE + rb + col] = aUd[m][ot][1][reg];
          P[2 * XPLANE + rb + col] = aUs[m][ot][0][reg];
          P[3 * XPLANE + rb + col] = aUs[m][ot][1][reg];
        }
      }
    }
  }
}

// ---------------------------------------------------------------------------
// Reduce 4 i-split partials
// ---------------------------------------------------------------------------
__global__ __launch_bounds__(256) void k_reduce4(
    const float* __restrict__ Part,
    float* __restrict__ UdFre, float* __restrict__ UdFim,
    float* __restrict__ UsFre, float* __restrict__ UsFim)
{
  int idx = blockIdx.x * 256 + threadIdx.x;
  if (idx >= XPLANE) return;
  float s0 = 0.f, s1 = 0.f, s2 = 0.f, s3 = 0.f;
#pragma unroll
  for (int is = 0; is < 4; ++is) {
    const float* p = Part + (size_t)is * 4 * XPLANE;
    s0 += p[0 * XPLANE + idx];
    s1 += p[1 * XPLANE + idx];
    s2 += p[2 * XPLANE + idx];
    s3 += p[3 * XPLANE + idx];
  }
  UdFre[idx] = s0; UdFim[idx] = s1; UsFre[idx] = s2; UsFim[idx] = s3;
}

// ---------------------------------------------------------------------------
// Fallback scalar mix (workspace too small for repack arenas)
// ---------------------------------------------------------------------------
__global__ __launch_bounds__(512) void k_mix_fb(
    const float* __restrict__ XDre, const float* __restrict__ XDim,
    const float* __restrict__ XVre, const float* __restrict__ XVim,
    const float* __restrict__ war, const float* __restrict__ wai,
    const float* __restrict__ wbr, const float* __restrict__ wbi,
    const float* __restrict__ wcr, const float* __restrict__ wci,
    float* __restrict__ UdFre, float* __restrict__ UdFim,
    float* __restrict__ UsFre, float* __restrict__ UsFim)
{
  const int f = blockIdx.x;
  const int ot = blockIdx.y;
  const int lane = threadIdx.x & 63;
  const int rg = threadIdx.x >> 6;
  const int rbase = (rg < 4) ? rg * 6 : 24 + (rg - 4) * 5;
  const int rcnt = (rg < 4) ? 6 : 5;
  const int o0 = (ot << 7) + lane;
  __shared__ float4 sx[NROWS * 64];
  float udr[6][2] = {}, udi[6][2] = {}, usr[6][2] = {}, usi[6][2] = {};
  for (int i0 = 0; i0 < 512; i0 += 64) {
    __syncthreads();
    for (int idx = threadIdx.x; idx < NROWS * 64; idx += 512) {
      int r = idx >> 6, il = idx & 63;
      size_t xb = ((size_t)f * NROWS + r) * CKD + i0 + il;
      sx[idx] = make_float4(XDre[xb], XDim[xb], XVre[xb], XVim[xb]);
    }
    __syncthreads();
    for (int ii = 0; ii < 64; ++ii) {
      int i = i0 + ii;
      size_t wo = ((((size_t)i << 9) + o0) << 4) + f;
      float4 wa0 = make_float4(war[wo], wai[wo], wbr[wo], wbi[wo]);
      float2 wc0 = make_float2(wcr[wo], wci[wo]);
      size_t w1 = wo + (64u << 4);
      float4 wa1 = make_float4(war[w1], wai[w1], wbr[w1], wbi[w1]);
      float2 wc1 = make_float2(wcr[w1], wci[w1]);
#pragma unroll
      for (int rr = 0; rr < 6; ++rr) {
        if (rr < rcnt) {
          float4 xv = sx[((rbase + rr) << 6) + ii];
          udr[rr][0] += xv.x * wa0.x - xv.y * wa0.y + xv.z * wa0.z - xv.w * wa0.w;
          udi[rr][0] += xv.x * wa0.y + xv.y * wa0.x + xv.z * wa0.w + xv.w * wa0.z;
          usr[rr][0] += xv.x * wc0.x - xv.y * wc0.y;
          usi[rr][0] += xv.x * wc0.y + xv.y * wc0.x;
          udr[rr][1] += xv.x * wa1.x - xv.y * wa1.y + xv.z * wa1.z - xv.w * wa1.w;
          udi[rr][1] += xv.x * wa1.y + xv.y * wa1.x + xv.z * wa1.w + xv.w * wa1.z;
          usr[rr][1] += xv.x * wc1.x - xv.y * wc1.y;
          usi[rr][1] += xv.x * wc1.y + xv.y * wc1.x;
        }
      }
    }
  }
#pragma unroll
  for (int rr = 0; rr < 6; ++rr) {
    if (rr < rcnt) {
      size_t rb_ = ((size_t)f * NROWS + rbase + rr) * CKD;
      UdFre[rb_ + o0] = udr[rr][0];      UdFre[rb_ + o0 + 64] = udr[rr][1];
      UdFim[rb_ + o0] = udi[rr][0];      UdFim[rb_ + o0 + 64] = udi[rr][1];
      UsFre[rb_ + o0] = usr[rr][0];      UsFre[rb_ + o0 + 64] = usr[rr][1];
      UsFim[rb_ + o0] = usi[rr][0];      UsFim[rb_ + o0 + 64] = usi[rr][1];
    }
  }
}

// ---------------------------------------------------------------------------
// Inverse truncated DFT
// ---------------------------------------------------------------------------
__global__ __launch_bounds__(256) void k_idft(
    const float* __restrict__ UdFre, const float* __restrict__ UdFim,
    const float* __restrict__ UsFre, const float* __restrict__ UsFim,
    float* __restrict__ UdT, float* __restrict__ UsT)
{
  __shared__ float2 tw[128];  // [f][8]
  int bx = blockIdx.x, j = 1;
  for (;;) {
    int c = (4096 >> j) >> 3; if (c < 1) c = 1;
    if (bx < c) break;
    bx -= c; ++j;
  }
  const int L = 4096 >> j;
  const int l = imin(16, (L >> 1) + 1);
  const int t0 = bx << 3;
  const int b = blockIdx.y;
  const int r = (j - 1) * 4 + b;
  if (threadIdx.x < 128) {
    int ff = threadIdx.x >> 3, tl = threadIdx.x & 7;
    int t = t0 + tl;
    int m = (2 * ff * t) & (2 * L - 1);
    float xang = (float)m / (float)L;
    float wgt = (ff == 0 || 2 * ff == L) ? 1.0f : 2.0f;
    float sc = wgt / (float)L;
    tw[threadIdx.x] = make_float2(cospif(xang) * sc, sinpif(xang) * sc);
  }
  __syncthreads();
  const int o = threadIdx.x << 1;
  float2 ud[8], us[8];
#pragma unroll
  for (int tl = 0; tl < 8; ++tl) { ud[tl] = make_float2(0.f, 0.f); us[tl] = make_float2(0.f, 0.f); }
  for (int ff = 0; ff < l; ++ff) {
    size_t bidx = ((size_t)ff * NROWS + r) * CKD + o;
    float2 er = *(const float2*)(UdFre + bidx);
    float2 ei = *(const float2*)(UdFim + bidx);
    float2 sr = *(const float2*)(UsFre + bidx);
    float2 si = *(const float2*)(UsFim + bidx);
#pragma unroll
    for (int tl = 0; tl < 8; ++tl) {
      float2 cs = tw[(ff << 3) + tl];
      ud[tl].x += er.x * cs.x - ei.x * cs.y;
      ud[tl].y += er.y * cs.x - ei.y * cs.y;
      us[tl].x += sr.x * cs.x - si.x * cs.y;
      us[tl].y += sr.y * cs.x - si.y * cs.y;
    }
  }
  int tmax = imin(8, L - t0);
  size_t obase = ((size_t)(4 * (4096 - (4096 >> (j - 1))) + b * L + t0)) * CKD + o;
  for (int tl = 0; tl < tmax; ++tl) {
    *(float2*)(UdT + obase + (size_t)tl * CKD) = ud[tl];
    *(float2*)(UsT + obase + (size_t)tl * CKD) = us[tl];
  }
}

// ---------------------------------------------------------------------------
// Fused reconstruction tree: block loads ir input rows, expands NL levels in
// LDS (intermediate v never hits global), writes ir<<NL rows to Vout.
// grid = (LcIn/ir, 4). Levels processed: j0, j0-1, ..., j0-NL+1.
// ---------------------------------------------------------------------------
__global__ __launch_bounds__(256) void k_recon_tree(
    const float* __restrict__ Vin, const float* __restrict__ UdT,
    const float* __restrict__ UsT, const float* __restrict__ rc_e,
    const float* __restrict__ rc_o, float* __restrict__ Vout,
    int j0, int NL, int ir, int pin, int pout)
{
  __shared__ float Re[128], Ro[128];
  __shared__ float bufA[16 * 512];
  __shared__ float bufB[16 * 512];
  const int tid = threadIdx.x;
  if (tid < 128) Re[tid] = rc_e[tid];
  else Ro[tid - 128] = rc_o[tid - 128];
  const int b = blockIdx.y;
  const int r0 = blockIdx.x * ir;

  for (int q = tid; q < ir * 128; q += 256) {
    int rr = q >> 7, c4 = (q & 127) << 2;
    *(float4*)&bufA[rr * 512 + c4] =
        *(const float4*)(Vin + ((size_t)b * pin + r0 + rr) * CKD + c4);
  }
  __syncthreads();

  float* rd = bufA;
  float* wr = bufB;
  int rows = ir;
  for (int m = 0; m < NL; ++m) {
    const int j = j0 - m;
    const int Lc = 4096 >> j;
    const size_t ab = 4ull * (4096 - (4096 >> (j - 1))) * CKD;
    const int g0 = r0 << m;
    for (int task = tid; task < rows * 64; task += 256) {
      int s = task >> 6, c = task & 63;
      size_t arow = ab + ((size_t)b * Lc + g0 + s) * CKD + (c << 3);
      const float* vp = rd + s * 512 + (c << 3);
      float a[16];
      {
        float4 t0_ = *(const float4*)vp;
        float4 t1_ = *(const float4*)(vp + 4);
        float4 u0 = *(const float4*)(UsT + arow);
        float4 u1 = *(const float4*)(UsT + arow + 4);
        a[0]=t0_.x+u0.x; a[1]=t0_.y+u0.y; a[2]=t0_.z+u0.z; a[3]=t0_.w+u0.w;
        a[4]=t1_.x+u1.x; a[5]=t1_.y+u1.y; a[6]=t1_.z+u1.z; a[7]=t1_.w+u1.w;
        float4 d0 = *(const float4*)(UdT + arow);
        float4 d1 = *(const float4*)(UdT + arow + 4);
        a[8]=d0.x; a[9]=d0.y; a[10]=d0.z; a[11]=d0.w;
        a[12]=d1.x; a[13]=d1.y; a[14]=d1.z; a[15]=d1.w;
      }
      float xe[8] = {}, xo[8] = {};
#pragma unroll
      for (int mm = 0; mm < 16; ++mm)
#pragma unroll
        for (int k = 0; k < 8; ++k) {
          xe[k] += a[mm] * Re[mm * 8 + k];
          xo[k] += a[mm] * Ro[mm * 8 + k];
        }
      float* we = wr + (2 * s) * 512 + (c << 3);
      *(float4*)we         = make_float4(xe[0], xe[1], xe[2], xe[3]);
      *(float4*)(we + 4)   = make_float4(xe[4], xe[5], xe[6], xe[7]);
      *(float4*)(we + 512) = make_float4(xo[0], xo[1], xo[2], xo[3]);
      *(float4*)(we + 516) = make_float4(xo[4], xo[5], xo[6], xo[7]);
    }
    __syncthreads();
    float* t = rd; rd = wr; wr = t;
    rows <<= 1;
  }

  for (int q = tid; q < rows * 128; q += 256) {
    int rr = q >> 7, c4 = (q & 127) << 2;
    *(float4*)(Vout + ((size_t)b * pout + (r0 << NL) + rr) * CKD + c4) =
        *(const float4*)&rd[rr * 512 + c4];
  }
}

// ---------------------------------------------------------------------------
extern "C" void kernel_launch(void* const* d_in, const int* in_sizes, int n_in,
                              void* d_out, int out_size, void* d_ws, size_t ws_size,
                              hipStream_t stream)
{
  const float* x     = (const float*)d_in[0];
  const float* Lk0_w = (const float*)d_in[1];
  const float* Lk0_b = (const float*)d_in[2];
  const float* Lk1_w = (const float*)d_in[3];
  const float* Lk1_b = (const float*)d_in[4];
  const float* T0_w  = (const float*)d_in[5];
  const float* T0_b  = (const float*)d_in[6];
  const float* Ar = (const float*)d_in[7];
  const float* Ai = (const float*)d_in[8];
  const float* Br = (const float*)d_in[9];
  const float* Bi = (const float*)d_in[10];
  const float* Cr = (const float*)d_in[11];
  const float* Ci = (const float*)d_in[12];
  const float* ec_s = (const float*)d_in[13];
  const float* ec_d = (const float*)d_in[14];
  const float* rc_e = (const float*)d_in[15];
  const float* rc_o = (const float*)d_in[16];
  float* out = (float*)d_out;

  // workspace layout (floats)
  float* w = (float*)d_ws;
  float* V0 = w;   w += (size_t)4 * 4096 * 512;  // RA rows 0..7; SA/SB stages
  float* VD = w;   w += (size_t)4 * 4094 * 512;  // aliased as UsT
  float* DD = w;   w += (size_t)4 * 4094 * 512;  // aliased as UdT; late: Cb
  float* RB = w;   w += (size_t)4 * 4096 * 512;  // early: Xb; mid: Part; late: recon out
  float* XDre = w; w += XPLANE;
  float* XDim = w; w += XPLANE;
  float* XVre = w; w += XPLANE;
  float* XVim = w; w += XPLANE;
  float* UdFre = w; w += XPLANE;   // early: Wb0/Wb1 bf16
  float* UdFim = w; w += XPLANE;
  float* UsFre = w; w += XPLANE;
  float* UsFim = w; w += XPLANE;
  float* WT = w;
  float* RA = V0;
  float* SA = V0 + 4096;            // 4*16*512 = 32768 floats
  float* SB = V0 + 4096 + 32768;    // 4*256*512 = 524288 floats
  float* UdT = DD;
  float* UsT = VD;
  float* Part = RB;                 // 16*XPLANE = 5.77M <= 8.39M

  unsigned short* Xb  = (unsigned short*)RB;
  unsigned short* Cb  = (unsigned short*)DD;
  unsigned short* Wb0 = (unsigned short*)UdFre;
  unsigned short* Wb1 = (unsigned short*)UdFre;

  const size_t BASE_FLOATS = 36421632ull;
  const size_t WT_FLOATS   = 25165824ull;
  if (ws_size < BASE_FLOATS * 4) return;
  const bool use_wt = ws_size >= (BASE_FLOATS + WT_FLOATS) * 4;
  uint2*  W4b = (uint2*)WT;
  uint32* W2b = (uint32*)(WT + 8388608ull);
  unsigned short* AudP = (unsigned short*)(WT + 12582912ull);
  unsigned short* AusP = (unsigned short*)(WT + 13369344ull);

  // 1. bf16 converts + Lk0 GEMM (MFMA)
  k_cvt_x<<<dim3(4096), dim3(256), 0, stream>>>(x, Xb);
  k_cvt_gen<<<dim3(128), dim3(256), 0, stream>>>(Lk0_w, Wb0);
  k_gemm_bf16<<<dim3(128, 4), dim3(256), 0, stream>>>(Xb, Wb0, Lk0_b, V0);

  // 2. fused decomposition: levels 1-4, 5-8, 9-11
  k_decomp_tree<<<dim3(256, 4), dim3(256), 0, stream>>>(
      V0, ec_s, ec_d, DD, VD, 1, 4, 4096);
  k_decomp_tree<<<dim3(16, 4), dim3(256), 0, stream>>>(
      VD + 4ull * 3584 * 512, ec_s, ec_d, DD, VD, 5, 4, 256);
  // level-8 v arena base = 4*(4096 - (4096>>7)) = 4*4064  (was 4080: BUG fixed)
  k_decomp_tree<<<dim3(1, 4), dim3(256), 0, stream>>>(
      VD + 4ull * 4064 * 512, ec_s, ec_d, DD, VD, 9, 3, 16);

  // 3. T0 on v_11
  k_t0<<<dim3(2), dim3(256), 0, stream>>>(VD + (size_t)4 * 4092 * 512, T0_w, T0_b, RA);

  // 4. zero X accumulators
  hipMemsetAsync(XDre, 0, (size_t)4 * XPLANE * 4, stream);

  // 5. weight repack to packed bf16 [f][i][o]
  if (use_wt)
    k_transw6b<<<dim3(1024), dim3(256), 0, stream>>>(Ar, Ai, Br, Bi, Cr, Ci, W4b, W2b);

  // 6. forward DFTs (chunk=64, prefetch)
  k_fdft<<<dim3(68, 4, 2), dim3(256), 0, stream>>>(DD, VD, XDre, XDim, XVre, XVim);

  if (use_wt) {
    k_packA<<<dim3(384), dim3(256), 0, stream>>>(XDre, XDim, XVre, XVim, AudP, AusP);
    k_mixmm<<<dim3(16, 4, 4), dim3(256), 0, stream>>>(W4b, W2b, AudP, AusP, Part);
    k_reduce4<<<dim3((XPLANE + 255) / 256), dim3(256), 0, stream>>>(
        Part, UdFre, UdFim, UsFre, UsFim);
  } else {
    k_mix_fb<<<dim3(16, 4), dim3(512), 0, stream>>>(
        XDre, XDim, XVre, XVim, Ar, Ai, Br, Bi, Cr, Ci,
        UdFre, UdFim, UsFre, UsFim);
  }

  // 8. inverse DFTs into time-domain Ud/Us arenas
  k_idft<<<dim3(513, 4), dim3(256), 0, stream>>>(UdFre, UdFim, UsFre, UsFim, UdT, UsT);

  // 9. fused reconstruction: j=11..9 (RA->SA), j=8..5 (SA->SB), j=4..1 (SB->RB)
  k_recon_tree<<<dim3(1, 4), dim3(256), 0, stream>>>(
      RA, UdT, UsT, rc_e, rc_o, SA, 11, 3, 2, 2, 16);
  k_recon_tree<<<dim3(16, 4), dim3(256), 0, stream>>>(
      SA, UdT, UsT, rc_e, rc_o, SB, 8, 4, 1, 16, 256);
  k_recon_tree<<<dim3(256, 4), dim3(256), 0, stream>>>(
      SB, UdT, UsT, rc_e, rc_o, RB, 4, 4, 1, 256, 4096);

  // 10. Lk1 GEMM (MFMA)
  k_cvt_c<<<dim3(3072), dim3(256), 0, stream>>>(RB, Cb);
  k_cvt_gen<<<dim3(128), dim3(256), 0, stream>>>(Lk1_w, Wb1);
  k_gemm_bf16<<<dim3(96, 4), dim3(256), 0, stream>>>(Cb, Wb1, Lk1_b, out);
}